// Round 3
// baseline (1172.334 us; speedup 1.0000x reference)
//
#include <hip/hip_runtime.h>
#include <cstdint>
#include <cstddef>

#define N_NODES 65536
#define E_EDGES 65535
#define DIN     512
#define KDIM    1024
#define JDIM    1024
#define HEADS   4
#define DOUT    256

typedef short   short8  __attribute__((ext_vector_type(8)));
typedef unsigned short ushort8 __attribute__((ext_vector_type(8)));
typedef float   floatx4 __attribute__((ext_vector_type(4)));

__device__ inline float bf2f(unsigned short u){
  union { unsigned int i; float f; } c; c.i = ((unsigned int)u) << 16; return c.f;
}
__device__ inline unsigned short f2bf(float f){
  union { float f; unsigned int i; } c; c.f = f;
  unsigned int r = c.i + 0x7FFFu + ((c.i >> 16) & 1u);
  return (unsigned short)(r >> 16);
}
// map float -> uint with same ordering (ascending)
__device__ inline unsigned int okey(float f){
  union { float f; unsigned int u; } c; c.f = f;
  return (c.u & 0x80000000u) ? ~c.u : (c.u | 0x80000000u);
}
__device__ inline float unokey(unsigned int k){
  union { unsigned int u; float f; } c;
  c.u = (k & 0x80000000u) ? (k ^ 0x80000000u) : ~k;
  return c.f;
}
__device__ inline float leaky(float x){ return x >= 0.f ? x : 0.2f * x; }
__device__ inline float gelu_f(float x){
  return 0.5f * x * (1.f + tanhf(0.7978845608028654f * (x + 0.044715f * x * x * x)));
}

// watt[k][0..3] = sum_c gw[k][hd*256+c]*atts[hd][c]; [4..7] same with attd
__global__ void k_watt(const float* __restrict__ gw, const float* __restrict__ atts,
                       const float* __restrict__ attd, float* __restrict__ watt){
  int wave = threadIdx.x >> 6, lane = threadIdx.x & 63;
  int k = blockIdx.x*4 + wave;           // 256 blocks x 4 waves = 1024 rows
  int hd = lane >> 4;
  const float* gr = gw + (size_t)k*JDIM + lane*16;
  float vs = 0.f, vd = 0.f;
  #pragma unroll
  for (int j = 0; j < 16; j += 4){
    float4 g = *(const float4*)(gr + j);
    float4 s = *(const float4*)(atts + lane*16 + j);   // flat idx == hd*DOUT+c
    float4 d = *(const float4*)(attd + lane*16 + j);
    vs += g.x*s.x + g.y*s.y + g.z*s.z + g.w*s.w;
    vd += g.x*d.x + g.y*d.y + g.z*d.z + g.w*d.w;
  }
  for (int m2 = 1; m2 < 16; m2 <<= 1){ vs += __shfl_xor(vs, m2); vd += __shfl_xor(vd, m2); }
  if ((lane & 15) == 0){ watt[k*8 + hd] = vs; watt[k*8 + 4 + hd] = vd; }
}

// tatt[ty*8 + sd*4 + hd] = sum_c tc[ty][hd*256+c] * att{sd}[hd][c]
__global__ void k_tatt(const float* __restrict__ tc, const float* __restrict__ atts,
                       const float* __restrict__ attd, float* __restrict__ tatt){
  int lane = threadIdx.x;   // 64
  for (int o = 0; o < 16; o++){
    int ty = o >> 3, sd = (o >> 2) & 1, hd = o & 3;
    const float* av = sd ? attd : atts;
    float p = 0.f;
    #pragma unroll
    for (int cc = 0; cc < 4; cc++){
      int c = lane*4 + cc;
      p += tc[ty*JDIM + hd*256 + c] * av[hd*DOUT + c];
    }
    for (int sdel = 32; sdel; sdel >>= 1) p += __shfl_down(p, sdel);
    if (lane == 0) tatt[o] = p;
  }
}

// ---------------- score + bf16 cast + key + att dots (wave-per-row) ----------------
__global__ void k_prep(const float* __restrict__ x, const float* __restrict__ sr,
                       const float* __restrict__ nmask, const float* __restrict__ sw,
                       const float* __restrict__ sb, const float* __restrict__ watt,
                       const float* __restrict__ tatt, const int* __restrict__ tid,
                       unsigned short* __restrict__ xs, float* __restrict__ score,
                       unsigned int* __restrict__ key, float* __restrict__ asrc,
                       float* __restrict__ adst){
  int lane = threadIdx.x & 63, wv = threadIdx.x >> 6;
  int i = blockIdx.x*4 + wv;
  const float* xr  = x  + (size_t)i*DIN + 8*lane;
  const float* srr = sr + (size_t)i*DIN + 8*lane;
  float4 a0 = *(const float4*)(xr);
  float4 a1 = *(const float4*)(xr + 4);
  float4 b0 = *(const float4*)(srr);
  float4 b1 = *(const float4*)(srr + 4);
  float4 w0 = *(const float4*)(sw + 8*lane);
  float4 w1 = *(const float4*)(sw + 8*lane + 4);
  float4 w2 = *(const float4*)(sw + 512 + 8*lane);
  float4 w3 = *(const float4*)(sw + 512 + 8*lane + 4);
  double part = (double)a0.x*(double)w0.x + (double)a0.y*(double)w0.y
              + (double)a0.z*(double)w0.z + (double)a0.w*(double)w0.w
              + (double)a1.x*(double)w1.x + (double)a1.y*(double)w1.y
              + (double)a1.z*(double)w1.z + (double)a1.w*(double)w1.w
              + (double)b0.x*(double)w2.x + (double)b0.y*(double)w2.y
              + (double)b0.z*(double)w2.z + (double)b0.w*(double)w2.w
              + (double)b1.x*(double)w3.x + (double)b1.y*(double)w3.y
              + (double)b1.z*(double)w3.z + (double)b1.w*(double)w3.w;
  ushort8 oa, ob;
  oa[0]=f2bf(a0.x); oa[1]=f2bf(a0.y); oa[2]=f2bf(a0.z); oa[3]=f2bf(a0.w);
  oa[4]=f2bf(a1.x); oa[5]=f2bf(a1.y); oa[6]=f2bf(a1.z); oa[7]=f2bf(a1.w);
  ob[0]=f2bf(b0.x); ob[1]=f2bf(b0.y); ob[2]=f2bf(b0.z); ob[3]=f2bf(b0.w);
  ob[4]=f2bf(b1.x); ob[5]=f2bf(b1.y); ob[6]=f2bf(b1.z); ob[7]=f2bf(b1.w);
  *(ushort8*)(xs + (size_t)i*KDIM + 8*lane)       = oa;
  *(ushort8*)(xs + (size_t)i*KDIM + 512 + 8*lane) = ob;

  // att dots: a_src/a_dst = xin . (W @ att) over k rows this lane owns
  float xv[16];
  xv[0]=a0.x; xv[1]=a0.y; xv[2]=a0.z; xv[3]=a0.w;
  xv[4]=a1.x; xv[5]=a1.y; xv[6]=a1.z; xv[7]=a1.w;
  xv[8]=b0.x; xv[9]=b0.y; xv[10]=b0.z; xv[11]=b0.w;
  xv[12]=b1.x; xv[13]=b1.y; xv[14]=b1.z; xv[15]=b1.w;
  float4 ps = {0.f,0.f,0.f,0.f}, pd = {0.f,0.f,0.f,0.f};
  #pragma unroll
  for (int kk = 0; kk < 16; kk++){
    int krow = (kk < 8) ? (8*lane + kk) : (512 + 8*lane + (kk - 8));
    float4 wv0 = *(const float4*)(watt + krow*8);
    float4 wv1 = *(const float4*)(watt + krow*8 + 4);
    ps.x += xv[kk]*wv0.x; ps.y += xv[kk]*wv0.y; ps.z += xv[kk]*wv0.z; ps.w += xv[kk]*wv0.w;
    pd.x += xv[kk]*wv1.x; pd.y += xv[kk]*wv1.y; pd.z += xv[kk]*wv1.z; pd.w += xv[kk]*wv1.w;
  }
  for (int sdel = 32; sdel; sdel >>= 1){
    part += __shfl_down(part, sdel);
    ps.x += __shfl_down(ps.x, sdel); ps.y += __shfl_down(ps.y, sdel);
    ps.z += __shfl_down(ps.z, sdel); ps.w += __shfl_down(ps.w, sdel);
    pd.x += __shfl_down(pd.x, sdel); pd.y += __shfl_down(pd.y, sdel);
    pd.z += __shfl_down(pd.z, sdel); pd.w += __shfl_down(pd.w, sdel);
  }
  if (lane == 0){
    float fs = (float)(part + (double)sb[0]);
    float s  = fs * nmask[i];
    score[i] = s;
    float v = (s == 0.f) ? __builtin_inff() : s;
    key[i] = okey(v);
    int tt = tid[i];
    float4 os = { ps.x + tatt[tt*8 + 0], ps.y + tatt[tt*8 + 1],
                  ps.z + tatt[tt*8 + 2], ps.w + tatt[tt*8 + 3] };
    float4 od = { pd.x + tatt[tt*8 + 4], pd.y + tatt[tt*8 + 5],
                  pd.z + tatt[tt*8 + 6], pd.w + tatt[tt*8 + 7] };
    *(float4*)(asrc + (size_t)i*HEADS) = os;
    *(float4*)(adst + (size_t)i*HEADS) = od;
  }
}

__global__ void k_nnz(const float* __restrict__ score, int* scal){
  int i = blockIdx.x*256 + threadIdx.x;
  int nz = (score[i] != 0.f) ? 1 : 0;
  unsigned long long b = __ballot(nz);
  if ((threadIdx.x & 63) == 0) atomicAdd(&scal[0], (int)__popcll(b));
}

// scal: [0]=nnz [1]=prune [2]=k [3]=prefix/Kstar [4]=rank/need [5]=eqcnt
__global__ void k_initsel(int* scal){
  int nnz = scal[0];
  double prod = (double)nnz * 0.3;        // IEEE-identical to Python
  scal[1] = ((int)prod != 0) ? 1 : 0;
  int k = (int)(prod + 1.0);
  scal[2] = k; scal[3] = 0; scal[4] = k;
}

__global__ void k_hist(const unsigned int* __restrict__ key, unsigned int* __restrict__ hist,
                       const int* __restrict__ scal, int pass){
  __shared__ unsigned int lh[256];
  int t = threadIdx.x;
  lh[t] = 0; __syncthreads();
  int i = blockIdx.x*256 + t;
  unsigned int kv = key[i];
  unsigned int pref = (unsigned int)scal[3];
  bool ok = (pass == 0) || ((kv >> (32 - 8*pass)) == pref);
  if (ok) atomicAdd(&lh[(kv >> (24 - 8*pass)) & 255u], 1u);
  __syncthreads();
  if (lh[t]) atomicAdd(&hist[t], lh[t]);
}

__global__ void k_select(unsigned int* __restrict__ hist, int* __restrict__ scal){
  __shared__ unsigned int h[256];
  int t = threadIdx.x;
  h[t] = hist[t];
  __syncthreads();
  if (t == 0){
    unsigned int r = (unsigned int)scal[4];
    unsigned int cum = 0, pref = (unsigned int)scal[3];
    for (int b = 0; b < 256; b++){
      unsigned int c = h[b];
      if (cum + c >= r){
        scal[3] = (int)((pref << 8) | (unsigned int)b);
        scal[4] = (int)(r - cum);
        break;
      }
      cum += c;
    }
  }
  __syncthreads();
  hist[t] = 0;  // ready for next pass
}

__global__ void k_mark(const unsigned int* __restrict__ key, int* __restrict__ scal,
                       int* __restrict__ rem, int* __restrict__ eqlist){
  if (!scal[1]) return;
  int i = blockIdx.x*256 + threadIdx.x;
  unsigned int Ks = (unsigned int)scal[3];
  unsigned int kv = key[i];
  if (kv < Ks) rem[i] = 1;
  else if (kv == Ks){
    int p = atomicAdd(&scal[5], 1);
    if (p < 4096) eqlist[p] = i;
  }
}

__global__ void k_ties(int* __restrict__ scal, int* __restrict__ eqlist, int* __restrict__ rem){
  if (!scal[1]) return;
  int m = scal[5]; if (m > 4096) m = 4096;
  int need = scal[4]; if (need > m) need = m;
  for (int it = 0; it < need; it++){          // lowest indices first (top_k tie rule)
    int best = 0x7FFFFFFF, bj = -1;
    for (int j = 0; j < m; j++){ int v = eqlist[j]; if (v < best){ best = v; bj = j; } }
    if (bj < 0) break;
    rem[best] = 1; eqlist[bj] = 0x7FFFFFFF;
  }
}

// one of 5 parent-climb iterations (rem[0]==0 guaranteed)
__global__ void k_remap(const int* __restrict__ pin, const int* __restrict__ rem,
                        int* __restrict__ pout){
  int e = blockIdx.x*256 + threadIdx.x;
  if (e >= E_EDGES) return;
  int p = pin[e];
  pout[e] = rem[p] ? (p == 0 ? 0 : pin[p-1]) : p;
}

// masked edges (child removed) are ALL (0,0) with alpha == node0 self-loop alpha;
// exclude them (dstF=-1) and account analytically with weight k on node 0.
__global__ void k_edges(const int* __restrict__ srcIn, const int* __restrict__ pfin,
                        const int* __restrict__ rem, int* __restrict__ srcF,
                        int* __restrict__ dstF, int* __restrict__ cnt){
  int e = blockIdx.x*256 + threadIdx.x;
  if (e >= E_EDGES) return;
  int s = srcIn[e];
  if (rem[s]){ srcF[e] = 0; dstF[e] = -1; }
  else {
    srcF[e] = s;
    int d = pfin[e];
    dstF[e] = d;
    atomicAdd(&cnt[d], 1);
  }
}

__global__ void k_scan1(const int* __restrict__ cnt, int* __restrict__ offs,
                        int* __restrict__ bsum){
  int b = blockIdx.x, t = threadIdx.x, i = b*256 + t;
  int v = cnt[i];
  int lane = t & 63, wv = t >> 6;
  int xv = v;
  for (int o2 = 1; o2 < 64; o2 <<= 1){ int y = __shfl_up(xv, o2); if (lane >= o2) xv += y; }
  __shared__ int wt_[4];
  if (lane == 63) wt_[wv] = xv;
  __syncthreads();
  int add = 0;
  for (int k2 = 0; k2 < wv; k2++) add += wt_[k2];
  offs[i] = xv + add - v;
  if (t == 255) bsum[b] = xv + add;
}

__global__ void k_scan2(int* __restrict__ bsum){
  int t = threadIdx.x;
  int v = bsum[t];
  int lane = t & 63, wv = t >> 6;
  int xv = v;
  for (int o2 = 1; o2 < 64; o2 <<= 1){ int y = __shfl_up(xv, o2); if (lane >= o2) xv += y; }
  __shared__ int wt_[4];
  if (lane == 63) wt_[wv] = xv;
  __syncthreads();
  int add = 0;
  for (int k2 = 0; k2 < wv; k2++) add += wt_[k2];
  bsum[t] = xv + add - v;  // exclusive
}

__global__ void k_scan3(int* __restrict__ offs, const int* __restrict__ bsum,
                        int* __restrict__ cur){
  int b = blockIdx.x, t = threadIdx.x, i = b*256 + t;
  int v = offs[i] + bsum[b];
  offs[i] = v; cur[i] = v;
}

__global__ void k_fill(const int* __restrict__ dstF, int* __restrict__ cur,
                       int* __restrict__ elist){
  int e = blockIdx.x*256 + threadIdx.x;
  if (e >= E_EDGES) return;
  int d = dstF[e]; if (d < 0) return;
  int pos = atomicAdd(&cur[d], 1);
  elist[pos] = e;
}

// gat_w[0:1024][:] -> bf16 transposed (wt[j][k] = gat_w[k][j])
__global__ void k_wt(const float* __restrict__ gw, unsigned short* __restrict__ wtb){
  __shared__ float tile[32][33];
  int kt = blockIdx.x*32, jt = blockIdx.y*32;
  int tx = threadIdx.x, ty = threadIdx.y;    // (32,8)
  for (int r = ty; r < 32; r += 8) tile[r][tx] = gw[(size_t)(kt+r)*JDIM + jt + tx];
  __syncthreads();
  for (int r = ty; r < 32; r += 8) wtb[(size_t)(jt+r)*KDIM + kt + tx] = f2bf(tile[tx][r]);
}

// tc[t][j] = sum_c gelu(emb_w[t][c]+emb_b[c]) * gat_w[1024+c][j]  (2 distinct type rows)
// gelu hoisted to LDS (was: 256 tanhf per thread)
__global__ void k_tc(const float* __restrict__ embw, const float* __restrict__ embb,
                     const float* __restrict__ gw, float* __restrict__ tc){
  __shared__ float eg[2][DOUT];
  int t = threadIdx.x;
  eg[0][t] = gelu_f(embw[t] + embb[t]);
  eg[1][t] = gelu_f(embw[DOUT + t] + embb[t]);
  __syncthreads();
  int g = blockIdx.x*256 + t;   // 0..2047
  int te = g >> 10, j = g & 1023;
  float acc = 0.f;
  #pragma unroll 8
  for (int c = 0; c < DOUT; c++){
    acc += eg[te][c] * gw[(size_t)(KDIM + c)*JDIM + j];
  }
  tc[te*JDIM + j] = acc;
}

// 256x256-tile, BK=64, 8-wave, double-buffered 2-phase bf16 MFMA GEMM:
//   h = xs @ W (+ tc[type]) -> bf16
#define BKG 64
__global__ __launch_bounds__(512, 2) void k_gemm(const unsigned short* __restrict__ xs,
    const unsigned short* __restrict__ wtb, const float* __restrict__ tc,
    const int* __restrict__ tid, unsigned short* __restrict__ hmat){
  __shared__ unsigned short As[2][256*BKG];   // 32 KB per buffer
  __shared__ unsigned short Bs[2][256*BKG];   // total 128 KB LDS
  int bid = blockIdx.x;
  // bijective XCD swizzle (1024 blocks, 1024%8==0): the 4 jb-blocks sharing an
  // A-panel land on consecutive slots of one XCD -> A fetched from HBM once.
  int xcd = bid & 7, tq = bid >> 3;
  int jb = tq & 3, ip = (tq >> 2)*8 + xcd;     // ip in 0..255, jb in 0..3
  int rowbase = ip*256, colbase = jb*256;
  int t = threadIdx.x, wave = t >> 6, lane = t & 63;
  int wm = (wave >> 2)*128, wn = (wave & 3)*64;   // 2x4 wave grid, 128x64 per wave
  floatx4 acc[8][4];
  floatx4 zero = {0.f, 0.f, 0.f, 0.f};
  #pragma unroll
  for (int a = 0; a < 8; a++)
    #pragma unroll
    for (int b = 0; b < 4; b++) acc[a][b] = zero;

  // staging geometry: per round r (0..3), wave w stages chunk ci=r*8+w
  // = rows [ci*8, ci*8+8) x 64 cols; lane l covers LDS bytes ci*1024 + l*16
  // (lane-contiguous as global_load_lds requires).
  int srow = lane >> 3;        // 0..7 row within chunk
  int scol = (lane & 7)*8;     // element col offset (8 bf16 = 16 B)

  auto STAGE = [&](int buf, int kt){
    int k0 = kt*BKG;
    #pragma unroll
    for (int r = 0; r < 4; r++){
      int ci = r*8 + wave;
      int row = ci*8 + srow;
      const unsigned short* ga = xs  + (size_t)(rowbase + row)*KDIM + k0 + scol;
      __builtin_amdgcn_global_load_lds((const __attribute__((address_space(1))) void*)ga,
          (__attribute__((address_space(3))) void*)(&As[buf][ci*512 + lane*8]), 16, 0, 0);
      const unsigned short* gb = wtb + (size_t)(colbase + row)*KDIM + k0 + scol;
      __builtin_amdgcn_global_load_lds((const __attribute__((address_space(1))) void*)gb,
          (__attribute__((address_space(3))) void*)(&Bs[buf][ci*512 + lane*8]), 16, 0, 0);
    }
  };

  int rr = lane & 15, rq = (lane >> 4)*8;
  auto COMPUTE = [&](int buf){
    #pragma unroll
    for (int ks = 0; ks < 2; ks++){
      short8 af[8], bfr[4];
      #pragma unroll
      for (int mi = 0; mi < 8; mi++)
        af[mi]  = *(const short8*)(&As[buf][(wm + mi*16 + rr)*BKG + ks*32 + rq]);
      #pragma unroll
      for (int ni = 0; ni < 4; ni++)
        bfr[ni] = *(const short8*)(&Bs[buf][(wn + ni*16 + rr)*BKG + ks*32 + rq]);
      #pragma unroll
      for (int mi = 0; mi < 8; mi++)
        #pragma unroll
        for (int ni = 0; ni < 4; ni++)
          acc[mi][ni] = __builtin_amdgcn_mfma_f32_16x16x32_bf16(af[mi], bfr[ni], acc[mi][ni], 0, 0, 0);
    }
  };

  const int NT = KDIM / BKG;   // 16 K-tiles
  STAGE(0, 0);
  __syncthreads();             // implicit vmcnt(0) drain: tile 0 ready
  int cur = 0;
  for (int kt = 0; kt < NT - 1; kt++){
    STAGE(cur ^ 1, kt + 1);    // issue next-tile loads BEFORE compute
    COMPUTE(cur);              // MFMA on current tile hides the staging
    __syncthreads();           // one barrier/tile: drains vmcnt, next tile ready
    cur ^= 1;
  }
  COMPUTE(cur);                // epilogue tile (no prefetch)

  int q = lane >> 4, cc = lane & 15;
  #pragma unroll
  for (int mi = 0; mi < 8; mi++){
    #pragma unroll
    for (int reg = 0; reg < 4; reg++){
      int rowg = rowbase + wm + mi*16 + q*4 + reg;
      int tt = tid[rowg];
      #pragma unroll
      for (int ni = 0; ni < 4; ni++){
        int col = colbase + wn + ni*16 + cc;
        float v = acc[mi][ni][reg] + tc[tt*JDIM + col];
        hmat[(size_t)rowg*JDIM + col] = f2bf(v);
      }
    }
  }
}

// per-node softmax (in-block max+sum, replaces k_max/k_sum) + aggregate + gelu
__global__ void k_agg(const unsigned short* __restrict__ hmat, const int* __restrict__ srcF,
                      const float* __restrict__ asrc, const float* __restrict__ adst,
                      const int* __restrict__ offs, const int* __restrict__ cnt,
                      const int* __restrict__ elist, const float* __restrict__ gatb,
                      const int* __restrict__ scal, float* __restrict__ out){
  int n = blockIdx.x, t = threadIdx.x;
  int o0 = offs[n], c_ = cnt[n];
  __shared__ float mh_s[4], sh_s[4];
  int wave = t >> 6, lane = t & 63;
  if (wave == 0){
    int hd = lane >> 4, r = lane & 15;       // 16 lanes per head
    float adn = adst[n*HEADS + hd];
    float aself = leaky(asrc[n*HEADS + hd] + adn);
    float mx = aself;
    for (int q2 = r; q2 < c_; q2 += 16){
      int e = elist[o0 + q2];
      int s = srcF[e];
      float al = leaky(asrc[s*HEADS + hd] + adn);
      mx = fmaxf(mx, al);
    }
    for (int m2 = 1; m2 < 16; m2 <<= 1) mx = fmaxf(mx, __shfl_xor(mx, m2));
    float sm = 0.f;
    for (int q2 = r; q2 < c_; q2 += 16){
      int e = elist[o0 + q2];
      int s = srcF[e];
      float al = leaky(asrc[s*HEADS + hd] + adn);
      sm += expf(al - mx);
    }
    for (int m2 = 1; m2 < 16; m2 <<= 1) sm += __shfl_xor(sm, m2);
    if (r == 0){
      float wself = 1.f;
      if (n == 0 && scal[1]) wself = 1.f + (float)scal[2];  // k masked (0,0) copies + self
      sm += wself * expf(aself - mx);
      mh_s[hd] = mx; sh_s[hd] = sm + 1e-16f;
    }
  }
  __syncthreads();
  int hd = t >> 6;                     // 4*t in [hd*256,(hd+1)*256)
  float mh = mh_s[hd];
  float sh = sh_s[hd];
  float adn = adst[n*HEADS + hd];
  float a0 = 0.f, a1 = 0.f, a2 = 0.f, a3 = 0.f;
  { // self-loop (+ k masked copies on node 0)
    float al = leaky(asrc[n*HEADS + hd] + adn);
    float coef = expf(al - mh) / sh;
    if (n == 0 && scal[1]) coef *= (1.f + (float)scal[2]);
    ushort4 hv = *(const ushort4*)(hmat + (size_t)n*JDIM + 4*t);
    a0 += coef*bf2f(hv.x); a1 += coef*bf2f(hv.y); a2 += coef*bf2f(hv.z); a3 += coef*bf2f(hv.w);
  }
  for (int q2 = 0; q2 < c_; q2++){
    int e = elist[o0 + q2];
    int s = srcF[e];
    float al = leaky(asrc[s*HEADS + hd] + adn);
    float coef = expf(al - mh) / sh;
    ushort4 hv = *(const ushort4*)(hmat + (size_t)s*JDIM + 4*t);
    a0 += coef*bf2f(hv.x); a1 += coef*bf2f(hv.y); a2 += coef*bf2f(hv.z); a3 += coef*bf2f(hv.w);
  }
  const float4 gb = *(const float4*)(gatb + 4*t);
  float4 ov;
  ov.x = gelu_f(a0 + gb.x); ov.y = gelu_f(a1 + gb.y);
  ov.z = gelu_f(a2 + gb.z); ov.w = gelu_f(a3 + gb.w);
  *(float4*)(out + (size_t)n*JDIM + 4*t) = ov;
}

__global__ void k_nm(const float* __restrict__ nmask, const int* __restrict__ rem,
                     float* __restrict__ nmout){
  int i = blockIdx.x*256 + threadIdx.x;
  float u = (i == 0) ? 1.f : (1.f - (float)rem[i]);
  nmout[i] = nmask[i] * u;
}

extern "C" void kernel_launch(void* const* d_in, const int* in_sizes, int n_in,
                              void* d_out, int out_size, void* d_ws, size_t ws_size,
                              hipStream_t stream){
  (void)in_sizes; (void)n_in; (void)out_size; (void)ws_size;
  const float* x    = (const float*)d_in[0];
  const int*  eidx  = (const int*)d_in[1];
  const float* sr   = (const float*)d_in[3];
  const float* nmask= (const float*)d_in[4];
  const int*  tid   = (const int*)d_in[5];
  const float* sw   = (const float*)d_in[6];
  const float* sb   = (const float*)d_in[7];
  const float* embw = (const float*)d_in[8];
  const float* embb = (const float*)d_in[9];
  const float* gw   = (const float*)d_in[10];
  const float* atts = (const float*)d_in[11];
  const float* attd = (const float*)d_in[12];
  const float* gatb = (const float*)d_in[13];
  float* out = (float*)d_out;

  char* w = (char*)d_ws;
  size_t o = 0;
  auto alloc = [&](size_t bytes){ size_t r = o; o += (bytes + 255) & ~(size_t)255; return r; };
  // zeroed region (single memset)
  size_t o_cnt  = alloc((size_t)N_NODES*4);
  size_t o_rem  = alloc((size_t)N_NODES*4);
  size_t o_hist = alloc(256*4);
  size_t o_scal = alloc(64);
  size_t o_eq   = alloc(4096*4);
  size_t zero_bytes = o;
  // not zeroed
  size_t o_score= alloc((size_t)N_NODES*4);
  size_t o_key  = alloc((size_t)N_NODES*4);
  size_t o_pA   = alloc((size_t)E_EDGES*4);
  size_t o_pB   = alloc((size_t)E_EDGES*4);
  size_t o_srcF = alloc((size_t)E_EDGES*4);
  size_t o_dstF = alloc((size_t)E_EDGES*4);
  size_t o_off  = alloc((size_t)N_NODES*4);
  size_t o_cur  = alloc((size_t)N_NODES*4);
  size_t o_el   = alloc((size_t)E_EDGES*4);
  size_t o_bsum = alloc(256*4);
  size_t o_asrc = alloc((size_t)N_NODES*HEADS*4);
  size_t o_adst = alloc((size_t)N_NODES*HEADS*4);
  size_t o_tc   = alloc((size_t)2*JDIM*4);
  size_t o_watt = alloc((size_t)KDIM*8*4);
  size_t o_tatt = alloc(16*4);
  size_t o_wt   = alloc((size_t)JDIM*KDIM*2);
  size_t o_xs   = alloc((size_t)N_NODES*KDIM*2);
  size_t o_h    = alloc((size_t)N_NODES*JDIM*2);

  int* cnt   = (int*)(w + o_cnt);
  int* rem   = (int*)(w + o_rem);
  unsigned int* hist = (unsigned int*)(w + o_hist);
  int* scal  = (int*)(w + o_scal);
  int* eqlist= (int*)(w + o_eq);
  float* score = (float*)(w + o_score);
  unsigned int* key = (unsigned int*)(w + o_key);
  int* pA = (int*)(w + o_pA);
  int* pB = (int*)(w + o_pB);
  int* srcF = (int*)(w + o_srcF);
  int* dstF = (int*)(w + o_dstF);
  int* offs = (int*)(w + o_off);
  int* cur  = (int*)(w + o_cur);
  int* elist= (int*)(w + o_el);
  int* bsum = (int*)(w + o_bsum);
  float* asrc = (float*)(w + o_asrc);
  float* adst = (float*)(w + o_adst);
  float* tc = (float*)(w + o_tc);
  float* watt = (float*)(w + o_watt);
  float* tatt = (float*)(w + o_tatt);
  unsigned short* wtb = (unsigned short*)(w + o_wt);
  unsigned short* xs  = (unsigned short*)(w + o_xs);
  unsigned short* hmat= (unsigned short*)(w + o_h);

  hipMemsetAsync(w, 0, zero_bytes, stream);

  // small precomputes first (only depend on weights)
  k_watt<<<256, 256, 0, stream>>>(gw, atts, attd, watt);
  k_tc<<<8, 256, 0, stream>>>(embw, embb, gw, tc);
  k_tatt<<<1, 64, 0, stream>>>(tc, atts, attd, tatt);
  k_wt<<<dim3(32,32), dim3(32,8), 0, stream>>>(gw, wtb);

  k_prep<<<N_NODES/4, 256, 0, stream>>>(x, sr, nmask, sw, sb, watt, tatt, tid,
                                        xs, score, key, asrc, adst);
  k_nnz<<<N_NODES/256, 256, 0, stream>>>(score, scal);
  k_initsel<<<1, 1, 0, stream>>>(scal);
  for (int p = 0; p < 4; p++){
    k_hist<<<N_NODES/256, 256, 0, stream>>>(key, hist, scal, p);
    k_select<<<1, 256, 0, stream>>>(hist, scal);
  }
  k_mark<<<N_NODES/256, 256, 0, stream>>>(key, scal, rem, eqlist);
  k_ties<<<1, 1, 0, stream>>>(scal, eqlist, rem);

  const int* par_in = eidx + E_EDGES;   // edge_index row 1
  int egrid = (E_EDGES + 255)/256;
  k_remap<<<egrid, 256, 0, stream>>>(par_in, rem, pA);
  k_remap<<<egrid, 256, 0, stream>>>(pA, rem, pB);
  k_remap<<<egrid, 256, 0, stream>>>(pB, rem, pA);
  k_remap<<<egrid, 256, 0, stream>>>(pA, rem, pB);
  k_remap<<<egrid, 256, 0, stream>>>(pB, rem, pA);

  k_edges<<<egrid, 256, 0, stream>>>(eidx, pA, rem, srcF, dstF, cnt);
  k_scan1<<<256, 256, 0, stream>>>(cnt, offs, bsum);
  k_scan2<<<1, 256, 0, stream>>>(bsum);
  k_scan3<<<256, 256, 0, stream>>>(offs, bsum, cur);
  k_fill<<<egrid, 256, 0, stream>>>(dstF, cur, elist);

  k_gemm<<<1024, 512, 0, stream>>>(xs, wtb, tc, tid, hmat);

  k_agg<<<N_NODES, 256, 0, stream>>>(hmat, srcF, asrc, adst, offs, cnt,
                                     elist, gatb, scal, out);
  k_nm<<<N_NODES/256, 256, 0, stream>>>(nmask, rem, out + (size_t)N_NODES*JDIM);
}

// Round 5
// 1055.719 us; speedup vs baseline: 1.1105x; 1.1105x over previous
//
#include <hip/hip_runtime.h>
#include <cstdint>
#include <cstddef>

#define N_NODES 65536
#define E_EDGES 65535
#define DIN     512
#define KDIM    1024
#define JDIM    1024
#define HEADS   4
#define DOUT    256

typedef short   short8  __attribute__((ext_vector_type(8)));
typedef unsigned short ushort8 __attribute__((ext_vector_type(8)));
typedef float   floatx4 __attribute__((ext_vector_type(4)));

__device__ inline float bf2f(unsigned short u){
  union { unsigned int i; float f; } c; c.i = ((unsigned int)u) << 16; return c.f;
}
__device__ inline unsigned short f2bf(float f){
  union { float f; unsigned int i; } c; c.f = f;
  unsigned int r = c.i + 0x7FFFu + ((c.i >> 16) & 1u);
  return (unsigned short)(r >> 16);
}
// map float -> uint with same ordering (ascending)
__device__ inline unsigned int okey(float f){
  union { float f; unsigned int u; } c; c.f = f;
  return (c.u & 0x80000000u) ? ~c.u : (c.u | 0x80000000u);
}
__device__ inline float unokey(unsigned int k){
  union { unsigned int u; float f; } c;
  c.u = (k & 0x80000000u) ? (k ^ 0x80000000u) : ~k;
  return c.f;
}
__device__ inline float leaky(float x){ return x >= 0.f ? x : 0.2f * x; }
__device__ inline float gelu_f(float x){
  return 0.5f * x * (1.f + tanhf(0.7978845608028654f * (x + 0.044715f * x * x * x)));
}

// watt_s[k][hd] = sum_c gw[k][hd*256+c]*atts[hd][c];  watt_d same with attd
__global__ void k_watt(const float* __restrict__ gw, const float* __restrict__ atts,
                       const float* __restrict__ attd, float* __restrict__ watt_s,
                       float* __restrict__ watt_d){
  int wave = threadIdx.x >> 6, lane = threadIdx.x & 63;
  int k = blockIdx.x*4 + wave;           // 256 blocks x 4 waves = 1024 rows
  int hd = lane >> 4;
  const float* gr = gw + (size_t)k*JDIM + lane*16;
  float vs = 0.f, vd = 0.f;
  #pragma unroll
  for (int j = 0; j < 16; j += 4){
    float4 g = *(const float4*)(gr + j);
    float4 s = *(const float4*)(atts + lane*16 + j);   // flat idx == hd*DOUT+c
    float4 d = *(const float4*)(attd + lane*16 + j);
    vs += g.x*s.x + g.y*s.y + g.z*s.z + g.w*s.w;
    vd += g.x*d.x + g.y*d.y + g.z*d.z + g.w*d.w;
  }
  for (int m2 = 1; m2 < 16; m2 <<= 1){ vs += __shfl_xor(vs, m2); vd += __shfl_xor(vd, m2); }
  if ((lane & 15) == 0){ watt_s[k*4 + hd] = vs; watt_d[k*4 + hd] = vd; }
}

// tatt[ty*8 + sd*4 + hd] = sum_c tc[ty][hd*256+c] * att{sd}[hd][c]
__global__ void k_tatt(const float* __restrict__ tc, const float* __restrict__ atts,
                       const float* __restrict__ attd, float* __restrict__ tatt){
  int lane = threadIdx.x;   // 64
  for (int o = 0; o < 16; o++){
    int ty = o >> 3, sd = (o >> 2) & 1, hd = o & 3;
    const float* av = sd ? attd : atts;
    float p = 0.f;
    #pragma unroll
    for (int cc = 0; cc < 4; cc++){
      int c = lane*4 + cc;
      p += tc[ty*JDIM + hd*256 + c] * av[hd*DOUT + c];
    }
    for (int sdel = 32; sdel; sdel >>= 1) p += __shfl_down(p, sdel);
    if (lane == 0) tatt[o] = p;
  }
}

// ---------------- score + bf16 cast + key + att dots (wave-per-row) ----------------
// k-ownership is STRIDED: lane l owns k in {l, l+64, ..., l+960}. All global
// accesses (x, sr, sw scalar; watt_s/watt_d float4) are lane-coalesced.
__global__ void k_prep(const float* __restrict__ x, const float* __restrict__ sr,
                       const float* __restrict__ nmask, const float* __restrict__ sw,
                       const float* __restrict__ sb, const float* __restrict__ watt_s,
                       const float* __restrict__ watt_d, const float* __restrict__ tatt,
                       const int* __restrict__ tid, unsigned short* __restrict__ xs,
                       float* __restrict__ score, unsigned int* __restrict__ key,
                       float* __restrict__ asrc, float* __restrict__ adst){
  int lane = threadIdx.x & 63, wv = threadIdx.x >> 6;
  int i = blockIdx.x*4 + wv;
  const float* xr  = x  + (size_t)i*DIN;
  const float* srr = sr + (size_t)i*DIN;
  unsigned short* xo = xs + (size_t)i*KDIM;
  double part = 0.0;
  float4 ps = {0.f,0.f,0.f,0.f}, pd = {0.f,0.f,0.f,0.f};
  #pragma unroll
  for (int j = 0; j < 8; j++){
    int k = lane + 64*j;
    float va = xr[k];
    float vb = srr[k];
    part += (double)va*(double)sw[k] + (double)vb*(double)sw[512 + k];
    float4 sA = *(const float4*)(watt_s + (size_t)k*4);
    float4 dA = *(const float4*)(watt_d + (size_t)k*4);
    float4 sB = *(const float4*)(watt_s + (size_t)(512 + k)*4);
    float4 dB = *(const float4*)(watt_d + (size_t)(512 + k)*4);
    ps.x += va*sA.x + vb*sB.x; ps.y += va*sA.y + vb*sB.y;
    ps.z += va*sA.z + vb*sB.z; ps.w += va*sA.w + vb*sB.w;
    pd.x += va*dA.x + vb*dB.x; pd.y += va*dA.y + vb*dB.y;
    pd.z += va*dA.z + vb*dB.z; pd.w += va*dA.w + vb*dB.w;
    xo[k]       = f2bf(va);
    xo[512 + k] = f2bf(vb);
  }
  for (int sdel = 32; sdel; sdel >>= 1){
    part += __shfl_down(part, sdel);
    ps.x += __shfl_down(ps.x, sdel); ps.y += __shfl_down(ps.y, sdel);
    ps.z += __shfl_down(ps.z, sdel); ps.w += __shfl_down(ps.w, sdel);
    pd.x += __shfl_down(pd.x, sdel); pd.y += __shfl_down(pd.y, sdel);
    pd.z += __shfl_down(pd.z, sdel); pd.w += __shfl_down(pd.w, sdel);
  }
  if (lane == 0){
    float fs = (float)(part + (double)sb[0]);
    float s  = fs * nmask[i];
    score[i] = s;
    float v = (s == 0.f) ? __builtin_inff() : s;
    key[i] = okey(v);
    int tt = tid[i];
    float4 os = { ps.x + tatt[tt*8 + 0], ps.y + tatt[tt*8 + 1],
                  ps.z + tatt[tt*8 + 2], ps.w + tatt[tt*8 + 3] };
    float4 od = { pd.x + tatt[tt*8 + 4], pd.y + tatt[tt*8 + 5],
                  pd.z + tatt[tt*8 + 6], pd.w + tatt[tt*8 + 7] };
    *(float4*)(asrc + (size_t)i*HEADS) = os;
    *(float4*)(adst + (size_t)i*HEADS) = od;
  }
}

__global__ void k_nnz(const float* __restrict__ score, int* scal){
  int i = blockIdx.x*256 + threadIdx.x;
  int nz = (score[i] != 0.f) ? 1 : 0;
  unsigned long long b = __ballot(nz);
  if ((threadIdx.x & 63) == 0) atomicAdd(&scal[0], (int)__popcll(b));
}

// scal: [0]=nnz [1]=prune [2]=k [3]=prefix/Kstar [4]=rank/need [5]=eqcnt
__global__ void k_initsel(int* scal){
  int nnz = scal[0];
  double prod = (double)nnz * 0.3;        // IEEE-identical to Python
  scal[1] = ((int)prod != 0) ? 1 : 0;
  int k = (int)(prod + 1.0);
  scal[2] = k; scal[3] = 0; scal[4] = k;
}

__global__ void k_hist(const unsigned int* __restrict__ key, unsigned int* __restrict__ hist,
                       const int* __restrict__ scal, int pass){
  __shared__ unsigned int lh[256];
  int t = threadIdx.x;
  lh[t] = 0; __syncthreads();
  int i = blockIdx.x*256 + t;
  unsigned int kv = key[i];
  unsigned int pref = (unsigned int)scal[3];
  bool ok = (pass == 0) || ((kv >> (32 - 8*pass)) == pref);
  if (ok) atomicAdd(&lh[(kv >> (24 - 8*pass)) & 255u], 1u);
  __syncthreads();
  if (lh[t]) atomicAdd(&hist[t], lh[t]);
}

__global__ void k_select(unsigned int* __restrict__ hist, int* __restrict__ scal){
  __shared__ unsigned int h[256];
  int t = threadIdx.x;
  h[t] = hist[t];
  __syncthreads();
  if (t == 0){
    unsigned int r = (unsigned int)scal[4];
    unsigned int cum = 0, pref = (unsigned int)scal[3];
    for (int b = 0; b < 256; b++){
      unsigned int c = h[b];
      if (cum + c >= r){
        scal[3] = (int)((pref << 8) | (unsigned int)b);
        scal[4] = (int)(r - cum);
        break;
      }
      cum += c;
    }
  }
  __syncthreads();
  hist[t] = 0;  // ready for next pass
}

__global__ void k_mark(const unsigned int* __restrict__ key, int* __restrict__ scal,
                       int* __restrict__ rem, int* __restrict__ eqlist){
  if (!scal[1]) return;
  int i = blockIdx.x*256 + threadIdx.x;
  unsigned int Ks = (unsigned int)scal[3];
  unsigned int kv = key[i];
  if (kv < Ks) rem[i] = 1;
  else if (kv == Ks){
    int p = atomicAdd(&scal[5], 1);
    if (p < 4096) eqlist[p] = i;
  }
}

__global__ void k_ties(int* __restrict__ scal, int* __restrict__ eqlist, int* __restrict__ rem){
  if (!scal[1]) return;
  int m = scal[5]; if (m > 4096) m = 4096;
  int need = scal[4]; if (need > m) need = m;
  for (int it = 0; it < need; it++){          // lowest indices first (top_k tie rule)
    int best = 0x7FFFFFFF, bj = -1;
    for (int j = 0; j < m; j++){ int v = eqlist[j]; if (v < best){ best = v; bj = j; } }
    if (bj < 0) break;
    rem[best] = 1; eqlist[bj] = 0x7FFFFFFF;
  }
}

// one of 5 parent-climb iterations (rem[0]==0 guaranteed)
__global__ void k_remap(const int* __restrict__ pin, const int* __restrict__ rem,
                        int* __restrict__ pout){
  int e = blockIdx.x*256 + threadIdx.x;
  if (e >= E_EDGES) return;
  int p = pin[e];
  pout[e] = rem[p] ? (p == 0 ? 0 : pin[p-1]) : p;
}

// masked edges (child removed) are ALL (0,0) with alpha == node0 self-loop alpha;
// exclude them (dstF=-1) and account analytically with weight k on node 0.
__global__ void k_edges(const int* __restrict__ srcIn, const int* __restrict__ pfin,
                        const int* __restrict__ rem, int* __restrict__ srcF,
                        int* __restrict__ dstF, int* __restrict__ cnt){
  int e = blockIdx.x*256 + threadIdx.x;
  if (e >= E_EDGES) return;
  int s = srcIn[e];
  if (rem[s]){ srcF[e] = 0; dstF[e] = -1; }
  else {
    srcF[e] = s;
    int d = pfin[e];
    dstF[e] = d;
    atomicAdd(&cnt[d], 1);
  }
}

__global__ void k_scan1(const int* __restrict__ cnt, int* __restrict__ offs,
                        int* __restrict__ bsum){
  int b = blockIdx.x, t = threadIdx.x, i = b*256 + t;
  int v = cnt[i];
  int lane = t & 63, wv = t >> 6;
  int xv = v;
  for (int o2 = 1; o2 < 64; o2 <<= 1){ int y = __shfl_up(xv, o2); if (lane >= o2) xv += y; }
  __shared__ int wt_[4];
  if (lane == 63) wt_[wv] = xv;
  __syncthreads();
  int add = 0;
  for (int k2 = 0; k2 < wv; k2++) add += wt_[k2];
  offs[i] = xv + add - v;
  if (t == 255) bsum[b] = xv + add;
}

__global__ void k_scan2(int* __restrict__ bsum){
  int t = threadIdx.x;
  int v = bsum[t];
  int lane = t & 63, wv = t >> 6;
  int xv = v;
  for (int o2 = 1; o2 < 64; o2 <<= 1){ int y = __shfl_up(xv, o2); if (lane >= o2) xv += y; }
  __shared__ int wt_[4];
  if (lane == 63) wt_[wv] = xv;
  __syncthreads();
  int add = 0;
  for (int k2 = 0; k2 < wv; k2++) add += wt_[k2];
  bsum[t] = xv + add - v;  // exclusive
}

__global__ void k_scan3(int* __restrict__ offs, const int* __restrict__ bsum,
                        int* __restrict__ cur){
  int b = blockIdx.x, t = threadIdx.x, i = b*256 + t;
  int v = offs[i] + bsum[b];
  offs[i] = v; cur[i] = v;
}

__global__ void k_fill(const int* __restrict__ dstF, int* __restrict__ cur,
                       int* __restrict__ elist){
  int e = blockIdx.x*256 + threadIdx.x;
  if (e >= E_EDGES) return;
  int d = dstF[e]; if (d < 0) return;
  int pos = atomicAdd(&cur[d], 1);
  elist[pos] = e;
}

// gat_w[0:1024][:] -> bf16 transposed (wt[j][k] = gat_w[k][j])
__global__ void k_wt(const float* __restrict__ gw, unsigned short* __restrict__ wtb){
  __shared__ float tile[32][33];
  int kt = blockIdx.x*32, jt = blockIdx.y*32;
  int tx = threadIdx.x, ty = threadIdx.y;    // (32,8)
  for (int r = ty; r < 32; r += 8) tile[r][tx] = gw[(size_t)(kt+r)*JDIM + jt + tx];
  __syncthreads();
  for (int r = ty; r < 32; r += 8) wtb[(size_t)(jt+r)*KDIM + kt + tx] = f2bf(tile[tx][r]);
}

// tc[t][j] = sum_c gelu(emb_w[t][c]+emb_b[c]) * gat_w[1024+c][j]  (2 distinct type rows)
// gelu hoisted to LDS (was: 256 tanhf per thread)
__global__ void k_tc(const float* __restrict__ embw, const float* __restrict__ embb,
                     const float* __restrict__ gw, float* __restrict__ tc){
  __shared__ float eg[2][DOUT];
  int t = threadIdx.x;
  eg[0][t] = gelu_f(embw[t] + embb[t]);
  eg[1][t] = gelu_f(embw[DOUT + t] + embb[t]);
  __syncthreads();
  int g = blockIdx.x*256 + t;   // 0..2047
  int te = g >> 10, j = g & 1023;
  float acc = 0.f;
  #pragma unroll 8
  for (int c = 0; c < DOUT; c++){
    acc += eg[te][c] * gw[(size_t)(KDIM + c)*JDIM + j];
  }
  tc[te*JDIM + j] = acc;
}

// 256x256-tile, BK=64, 8-wave, double-buffered 2-phase bf16 MFMA GEMM:
//   h = xs @ W (+ tc[type]) -> bf16
#define BKG 64
__global__ __launch_bounds__(512, 2) void k_gemm(const unsigned short* __restrict__ xs,
    const unsigned short* __restrict__ wtb, const float* __restrict__ tc,
    const int* __restrict__ tid, unsigned short* __restrict__ hmat){
  __shared__ unsigned short As[2][256*BKG];   // 32 KB per buffer
  __shared__ unsigned short Bs[2][256*BKG];   // total 128 KB LDS
  int bid = blockIdx.x;
  // bijective XCD swizzle (1024 blocks, 1024%8==0): the 4 jb-blocks sharing an
  // A-panel land on consecutive slots of one XCD -> A fetched from HBM once.
  int xcd = bid & 7, tq = bid >> 3;
  int jb = tq & 3, ip = (tq >> 2)*8 + xcd;     // ip in 0..255, jb in 0..3
  int rowbase = ip*256, colbase = jb*256;
  int t = threadIdx.x, wave = t >> 6, lane = t & 63;
  int wm = (wave >> 2)*128, wn = (wave & 3)*64;   // 2x4 wave grid, 128x64 per wave
  floatx4 acc[8][4];
  floatx4 zero = {0.f, 0.f, 0.f, 0.f};
  #pragma unroll
  for (int a = 0; a < 8; a++)
    #pragma unroll
    for (int b = 0; b < 4; b++) acc[a][b] = zero;

  // staging geometry: per round r (0..3), wave w stages chunk ci=r*8+w
  // = rows [ci*8, ci*8+8) x 64 cols; lane l covers LDS bytes ci*1024 + l*16
  // (lane-contiguous as global_load_lds requires).
  int srow = lane >> 3;        // 0..7 row within chunk
  int scol = (lane & 7)*8;     // element col offset (8 bf16 = 16 B)

  auto STAGE = [&](int buf, int kt){
    int k0 = kt*BKG;
    #pragma unroll
    for (int r = 0; r < 4; r++){
      int ci = r*8 + wave;
      int row = ci*8 + srow;
      const unsigned short* ga = xs  + (size_t)(rowbase + row)*KDIM + k0 + scol;
      __builtin_amdgcn_global_load_lds((const __attribute__((address_space(1))) void*)ga,
          (__attribute__((address_space(3))) void*)(&As[buf][ci*512 + lane*8]), 16, 0, 0);
      const unsigned short* gb = wtb + (size_t)(colbase + row)*KDIM + k0 + scol;
      __builtin_amdgcn_global_load_lds((const __attribute__((address_space(1))) void*)gb,
          (__attribute__((address_space(3))) void*)(&Bs[buf][ci*512 + lane*8]), 16, 0, 0);
    }
  };

  int rr = lane & 15, rq = (lane >> 4)*8;
  auto COMPUTE = [&](int buf){
    #pragma unroll
    for (int ks = 0; ks < 2; ks++){
      short8 af[8], bfr[4];
      #pragma unroll
      for (int mi = 0; mi < 8; mi++)
        af[mi]  = *(const short8*)(&As[buf][(wm + mi*16 + rr)*BKG + ks*32 + rq]);
      #pragma unroll
      for (int ni = 0; ni < 4; ni++)
        bfr[ni] = *(const short8*)(&Bs[buf][(wn + ni*16 + rr)*BKG + ks*32 + rq]);
      #pragma unroll
      for (int mi = 0; mi < 8; mi++)
        #pragma unroll
        for (int ni = 0; ni < 4; ni++)
          acc[mi][ni] = __builtin_amdgcn_mfma_f32_16x16x32_bf16(af[mi], bfr[ni], acc[mi][ni], 0, 0, 0);
    }
  };

  const int NT = KDIM / BKG;   // 16 K-tiles
  STAGE(0, 0);
  __syncthreads();             // implicit vmcnt(0) drain: tile 0 ready
  int cur = 0;
  for (int kt = 0; kt < NT - 1; kt++){
    STAGE(cur ^ 1, kt + 1);    // issue next-tile loads BEFORE compute
    COMPUTE(cur);              // MFMA on current tile hides the staging
    __syncthreads();           // one barrier/tile: drains vmcnt, next tile ready
    cur ^= 1;
  }
  COMPUTE(cur);                // epilogue tile (no prefetch)

  int q = lane >> 4, cc = lane & 15;
  #pragma unroll
  for (int mi = 0; mi < 8; mi++){
    #pragma unroll
    for (int reg = 0; reg < 4; reg++){
      int rowg = rowbase + wm + mi*16 + q*4 + reg;
      int tt = tid[rowg];
      #pragma unroll
      for (int ni = 0; ni < 4; ni++){
        int col = colbase + wn + ni*16 + cc;
        float v = acc[mi][ni][reg] + tc[tt*JDIM + col];
        hmat[(size_t)rowg*JDIM + col] = f2bf(v);
      }
    }
  }
}

// per-node softmax (in-block max+sum) + aggregate + gelu
__global__ void k_agg(const unsigned short* __restrict__ hmat, const int* __restrict__ srcF,
                      const float* __restrict__ asrc, const float* __restrict__ adst,
                      const int* __restrict__ offs, const int* __restrict__ cnt,
                      const int* __restrict__ elist, const float* __restrict__ gatb,
                      const int* __restrict__ scal, float* __restrict__ out){
  int n = blockIdx.x, t = threadIdx.x;
  int o0 = offs[n], c_ = cnt[n];
  __shared__ float mh_s[4], sh_s[4];
  int wave = t >> 6, lane = t & 63;
  if (wave == 0){
    int hd = lane >> 4, r = lane & 15;       // 16 lanes per head
    float adn = adst[n*HEADS + hd];
    float aself = leaky(asrc[n*HEADS + hd] + adn);
    float mx = aself;
    for (int q2 = r; q2 < c_; q2 += 16){
      int e = elist[o0 + q2];
      int s = srcF[e];
      float al = leaky(asrc[s*HEADS + hd] + adn);
      mx = fmaxf(mx, al);
    }
    for (int m2 = 1; m2 < 16; m2 <<= 1) mx = fmaxf(mx, __shfl_xor(mx, m2));
    float sm = 0.f;
    for (int q2 = r; q2 < c_; q2 += 16){
      int e = elist[o0 + q2];
      int s = srcF[e];
      float al = leaky(asrc[s*HEADS + hd] + adn);
      sm += expf(al - mx);
    }
    for (int m2 = 1; m2 < 16; m2 <<= 1) sm += __shfl_xor(sm, m2);
    if (r == 0){
      float wself = 1.f;
      if (n == 0 && scal[1]) wself = 1.f + (float)scal[2];  // k masked (0,0) copies + self
      sm += wself * expf(aself - mx);
      mh_s[hd] = mx; sh_s[hd] = sm + 1e-16f;
    }
  }
  __syncthreads();
  int hd = t >> 6;                     // 4*t in [hd*256,(hd+1)*256)
  float mh = mh_s[hd];
  float sh = sh_s[hd];
  float adn = adst[n*HEADS + hd];
  float a0 = 0.f, a1 = 0.f, a2 = 0.f, a3 = 0.f;
  { // self-loop (+ k masked copies on node 0)
    float al = leaky(asrc[n*HEADS + hd] + adn);
    float coef = expf(al - mh) / sh;
    if (n == 0 && scal[1]) coef *= (1.f + (float)scal[2]);
    ushort4 hv = *(const ushort4*)(hmat + (size_t)n*JDIM + 4*t);
    a0 += coef*bf2f(hv.x); a1 += coef*bf2f(hv.y); a2 += coef*bf2f(hv.z); a3 += coef*bf2f(hv.w);
  }
  for (int q2 = 0; q2 < c_; q2++){
    int e = elist[o0 + q2];
    int s = srcF[e];
    float al = leaky(asrc[s*HEADS + hd] + adn);
    float coef = expf(al - mh) / sh;
    ushort4 hv = *(const ushort4*)(hmat + (size_t)s*JDIM + 4*t);
    a0 += coef*bf2f(hv.x); a1 += coef*bf2f(hv.y); a2 += coef*bf2f(hv.z); a3 += coef*bf2f(hv.w);
  }
  const float4 gb = *(const float4*)(gatb + 4*t);
  float4 ov;
  ov.x = gelu_f(a0 + gb.x); ov.y = gelu_f(a1 + gb.y);
  ov.z = gelu_f(a2 + gb.z); ov.w = gelu_f(a3 + gb.w);
  *(float4*)(out + (size_t)n*JDIM + 4*t) = ov;
}

__global__ void k_nm(const float* __restrict__ nmask, const int* __restrict__ rem,
                     float* __restrict__ nmout){
  int i = blockIdx.x*256 + threadIdx.x;
  float u = (i == 0) ? 1.f : (1.f - (float)rem[i]);
  nmout[i] = nmask[i] * u;
}

extern "C" void kernel_launch(void* const* d_in, const int* in_sizes, int n_in,
                              void* d_out, int out_size, void* d_ws, size_t ws_size,
                              hipStream_t stream){
  (void)in_sizes; (void)n_in; (void)out_size; (void)ws_size;
  const float* x    = (const float*)d_in[0];
  const int*  eidx  = (const int*)d_in[1];
  const float* sr   = (const float*)d_in[3];
  const float* nmask= (const float*)d_in[4];
  const int*  tid   = (const int*)d_in[5];
  const float* sw   = (const float*)d_in[6];
  const float* sb   = (const float*)d_in[7];
  const float* embw = (const float*)d_in[8];
  const float* embb = (const float*)d_in[9];
  const float* gw   = (const float*)d_in[10];
  const float* atts = (const float*)d_in[11];
  const float* attd = (const float*)d_in[12];
  const float* gatb = (const float*)d_in[13];
  float* out = (float*)d_out;

  char* w = (char*)d_ws;
  size_t o = 0;
  auto alloc = [&](size_t bytes){ size_t r = o; o += (bytes + 255) & ~(size_t)255; return r; };
  // zeroed region (single memset)
  size_t o_cnt  = alloc((size_t)N_NODES*4);
  size_t o_rem  = alloc((size_t)N_NODES*4);
  size_t o_hist = alloc(256*4);
  size_t o_scal = alloc(64);
  size_t o_eq   = alloc(4096*4);
  size_t zero_bytes = o;
  // not zeroed
  size_t o_score= alloc((size_t)N_NODES*4);
  size_t o_key  = alloc((size_t)N_NODES*4);
  size_t o_pA   = alloc((size_t)E_EDGES*4);
  size_t o_pB   = alloc((size_t)E_EDGES*4);
  size_t o_srcF = alloc((size_t)E_EDGES*4);
  size_t o_dstF = alloc((size_t)E_EDGES*4);
  size_t o_off  = alloc((size_t)N_NODES*4);
  size_t o_cur  = alloc((size_t)N_NODES*4);
  size_t o_el   = alloc((size_t)E_EDGES*4);
  size_t o_bsum = alloc(256*4);
  size_t o_asrc = alloc((size_t)N_NODES*HEADS*4);
  size_t o_adst = alloc((size_t)N_NODES*HEADS*4);
  size_t o_tc   = alloc((size_t)2*JDIM*4);
  size_t o_wats = alloc((size_t)KDIM*4*4);
  size_t o_watd = alloc((size_t)KDIM*4*4);
  size_t o_tatt = alloc(16*4);
  size_t o_wt   = alloc((size_t)JDIM*KDIM*2);
  size_t o_xs   = alloc((size_t)N_NODES*KDIM*2);
  size_t o_h    = alloc((size_t)N_NODES*JDIM*2);

  int* cnt   = (int*)(w + o_cnt);
  int* rem   = (int*)(w + o_rem);
  unsigned int* hist = (unsigned int*)(w + o_hist);
  int* scal  = (int*)(w + o_scal);
  int* eqlist= (int*)(w + o_eq);
  float* score = (float*)(w + o_score);
  unsigned int* key = (unsigned int*)(w + o_key);
  int* pA = (int*)(w + o_pA);
  int* pB = (int*)(w + o_pB);
  int* srcF = (int*)(w + o_srcF);
  int* dstF = (int*)(w + o_dstF);
  int* offs = (int*)(w + o_off);
  int* cur  = (int*)(w + o_cur);
  int* elist= (int*)(w + o_el);
  int* bsum = (int*)(w + o_bsum);
  float* asrc = (float*)(w + o_asrc);
  float* adst = (float*)(w + o_adst);
  float* tc = (float*)(w + o_tc);
  float* watt_s = (float*)(w + o_wats);
  float* watt_d = (float*)(w + o_watd);
  float* tatt = (float*)(w + o_tatt);
  unsigned short* wtb = (unsigned short*)(w + o_wt);
  unsigned short* xs  = (unsigned short*)(w + o_xs);
  unsigned short* hmat= (unsigned short*)(w + o_h);

  hipMemsetAsync(w, 0, zero_bytes, stream);

  // small precomputes first (only depend on weights)
  k_watt<<<256, 256, 0, stream>>>(gw, atts, attd, watt_s, watt_d);
  k_tc<<<8, 256, 0, stream>>>(embw, embb, gw, tc);
  k_tatt<<<1, 64, 0, stream>>>(tc, atts, attd, tatt);
  k_wt<<<dim3(32,32), dim3(32,8), 0, stream>>>(gw, wtb);

  k_prep<<<N_NODES/4, 256, 0, stream>>>(x, sr, nmask, sw, sb, watt_s, watt_d, tatt,
                                        tid, xs, score, key, asrc, adst);
  k_nnz<<<N_NODES/256, 256, 0, stream>>>(score, scal);
  k_initsel<<<1, 1, 0, stream>>>(scal);
  for (int p = 0; p < 4; p++){
    k_hist<<<N_NODES/256, 256, 0, stream>>>(key, hist, scal, p);
    k_select<<<1, 256, 0, stream>>>(hist, scal);
  }
  k_mark<<<N_NODES/256, 256, 0, stream>>>(key, scal, rem, eqlist);
  k_ties<<<1, 1, 0, stream>>>(scal, eqlist, rem);

  const int* par_in = eidx + E_EDGES;   // edge_index row 1
  int egrid = (E_EDGES + 255)/256;
  k_remap<<<egrid, 256, 0, stream>>>(par_in, rem, pA);
  k_remap<<<egrid, 256, 0, stream>>>(pA, rem, pB);
  k_remap<<<egrid, 256, 0, stream>>>(pB, rem, pA);
  k_remap<<<egrid, 256, 0, stream>>>(pA, rem, pB);
  k_remap<<<egrid, 256, 0, stream>>>(pB, rem, pA);

  k_edges<<<egrid, 256, 0, stream>>>(eidx, pA, rem, srcF, dstF, cnt);
  k_scan1<<<256, 256, 0, stream>>>(cnt, offs, bsum);
  k_scan2<<<1, 256, 0, stream>>>(bsum);
  k_scan3<<<256, 256, 0, stream>>>(offs, bsum, cur);
  k_fill<<<egrid, 256, 0, stream>>>(dstF, cur, elist);

  k_gemm<<<1024, 512, 0, stream>>>(xs, wtb, tc, tid, hmat);

  k_agg<<<N_NODES, 256, 0, stream>>>(hmat, srcF, asrc, adst, offs, cnt,
                                     elist, gatb, scal, out);
  k_nm<<<N_NODES/256, 256, 0, stream>>>(nmask, rem, out + (size_t)N_NODES*JDIM);
}

// Round 6
// 1021.631 us; speedup vs baseline: 1.1475x; 1.0334x over previous
//
#include <hip/hip_runtime.h>
#include <cstdint>
#include <cstddef>

#define N_NODES 65536
#define E_EDGES 65535
#define DIN     512
#define KDIM    1024
#define JDIM    1024
#define HEADS   4
#define DOUT    256

typedef short   short8  __attribute__((ext_vector_type(8)));
typedef unsigned short ushort8 __attribute__((ext_vector_type(8)));
typedef float   floatx4 __attribute__((ext_vector_type(4)));

__device__ inline float bf2f(unsigned short u){
  union { unsigned int i; float f; } c; c.i = ((unsigned int)u) << 16; return c.f;
}
__device__ inline unsigned short f2bf(float f){
  union { float f; unsigned int i; } c; c.f = f;
  unsigned int r = c.i + 0x7FFFu + ((c.i >> 16) & 1u);
  return (unsigned short)(r >> 16);
}
// map float -> uint with same ordering (ascending)
__device__ inline unsigned int okey(float f){
  union { float f; unsigned int u; } c; c.f = f;
  return (c.u & 0x80000000u) ? ~c.u : (c.u | 0x80000000u);
}
__device__ inline float unokey(unsigned int k){
  union { unsigned int u; float f; } c;
  c.u = (k & 0x80000000u) ? (k ^ 0x80000000u) : ~k;
  return c.f;
}
__device__ inline float leaky(float x){ return x >= 0.f ? x : 0.2f * x; }
__device__ inline float gelu_f(float x){
  return 0.5f * x * (1.f + tanhf(0.7978845608028654f * (x + 0.044715f * x * x * x)));
}

// watt_s[k][hd] = sum_c gw[k][hd*256+c]*atts[hd][c];  watt_d same with attd
__global__ void k_watt(const float* __restrict__ gw, const float* __restrict__ atts,
                       const float* __restrict__ attd, float* __restrict__ watt_s,
                       float* __restrict__ watt_d){
  int wave = threadIdx.x >> 6, lane = threadIdx.x & 63;
  int k = blockIdx.x*4 + wave;           // 256 blocks x 4 waves = 1024 rows
  int hd = lane >> 4;
  const float* gr = gw + (size_t)k*JDIM + lane*16;
  float vs = 0.f, vd = 0.f;
  #pragma unroll
  for (int j = 0; j < 16; j += 4){
    float4 g = *(const float4*)(gr + j);
    float4 s = *(const float4*)(atts + lane*16 + j);   // flat idx == hd*DOUT+c
    float4 d = *(const float4*)(attd + lane*16 + j);
    vs += g.x*s.x + g.y*s.y + g.z*s.z + g.w*s.w;
    vd += g.x*d.x + g.y*d.y + g.z*d.z + g.w*d.w;
  }
  for (int m2 = 1; m2 < 16; m2 <<= 1){ vs += __shfl_xor(vs, m2); vd += __shfl_xor(vd, m2); }
  if ((lane & 15) == 0){ watt_s[k*4 + hd] = vs; watt_d[k*4 + hd] = vd; }
}

// tatt[ty*8 + sd*4 + hd] = sum_c tc[ty][hd*256+c] * att{sd}[hd][c]
__global__ void k_tatt(const float* __restrict__ tc, const float* __restrict__ atts,
                       const float* __restrict__ attd, float* __restrict__ tatt){
  int lane = threadIdx.x;   // 64
  for (int o = 0; o < 16; o++){
    int ty = o >> 3, sd = (o >> 2) & 1, hd = o & 3;
    const float* av = sd ? attd : atts;
    float p = 0.f;
    #pragma unroll
    for (int cc = 0; cc < 4; cc++){
      int c = lane*4 + cc;
      p += tc[ty*JDIM + hd*256 + c] * av[hd*DOUT + c];
    }
    for (int sdel = 32; sdel; sdel >>= 1) p += __shfl_down(p, sdel);
    if (lane == 0) tatt[o] = p;
  }
}

// ---------------- score + bf16 cast + key + att dots (wave-per-row) ----------------
// k-ownership is STRIDED: lane l owns k in {l, l+64, ..., l+960}. All global
// accesses (x, sr, sw scalar; watt_s/watt_d float4) are lane-coalesced.
__global__ void k_prep(const float* __restrict__ x, const float* __restrict__ sr,
                       const float* __restrict__ nmask, const float* __restrict__ sw,
                       const float* __restrict__ sb, const float* __restrict__ watt_s,
                       const float* __restrict__ watt_d, const float* __restrict__ tatt,
                       const int* __restrict__ tid, unsigned short* __restrict__ xs,
                       float* __restrict__ score, unsigned int* __restrict__ key,
                       float* __restrict__ asrc, float* __restrict__ adst){
  int lane = threadIdx.x & 63, wv = threadIdx.x >> 6;
  int i = blockIdx.x*4 + wv;
  const float* xr  = x  + (size_t)i*DIN;
  const float* srr = sr + (size_t)i*DIN;
  unsigned short* xo = xs + (size_t)i*KDIM;
  double part = 0.0;
  float4 ps = {0.f,0.f,0.f,0.f}, pd = {0.f,0.f,0.f,0.f};
  #pragma unroll
  for (int j = 0; j < 8; j++){
    int k = lane + 64*j;
    float va = xr[k];
    float vb = srr[k];
    part += (double)va*(double)sw[k] + (double)vb*(double)sw[512 + k];
    float4 sA = *(const float4*)(watt_s + (size_t)k*4);
    float4 dA = *(const float4*)(watt_d + (size_t)k*4);
    float4 sB = *(const float4*)(watt_s + (size_t)(512 + k)*4);
    float4 dB = *(const float4*)(watt_d + (size_t)(512 + k)*4);
    ps.x += va*sA.x + vb*sB.x; ps.y += va*sA.y + vb*sB.y;
    ps.z += va*sA.z + vb*sB.z; ps.w += va*sA.w + vb*sB.w;
    pd.x += va*dA.x + vb*dB.x; pd.y += va*dA.y + vb*dB.y;
    pd.z += va*dA.z + vb*dB.z; pd.w += va*dA.w + vb*dB.w;
    xo[k]       = f2bf(va);
    xo[512 + k] = f2bf(vb);
  }
  for (int sdel = 32; sdel; sdel >>= 1){
    part += __shfl_down(part, sdel);
    ps.x += __shfl_down(ps.x, sdel); ps.y += __shfl_down(ps.y, sdel);
    ps.z += __shfl_down(ps.z, sdel); ps.w += __shfl_down(ps.w, sdel);
    pd.x += __shfl_down(pd.x, sdel); pd.y += __shfl_down(pd.y, sdel);
    pd.z += __shfl_down(pd.z, sdel); pd.w += __shfl_down(pd.w, sdel);
  }
  if (lane == 0){
    float fs = (float)(part + (double)sb[0]);
    float s  = fs * nmask[i];
    score[i] = s;
    float v = (s == 0.f) ? __builtin_inff() : s;
    key[i] = okey(v);
    int tt = tid[i];
    float4 os = { ps.x + tatt[tt*8 + 0], ps.y + tatt[tt*8 + 1],
                  ps.z + tatt[tt*8 + 2], ps.w + tatt[tt*8 + 3] };
    float4 od = { pd.x + tatt[tt*8 + 4], pd.y + tatt[tt*8 + 5],
                  pd.z + tatt[tt*8 + 6], pd.w + tatt[tt*8 + 7] };
    *(float4*)(asrc + (size_t)i*HEADS) = os;
    *(float4*)(adst + (size_t)i*HEADS) = od;
  }
}

__global__ void k_nnz(const float* __restrict__ score, int* scal){
  int i = blockIdx.x*256 + threadIdx.x;
  int nz = (score[i] != 0.f) ? 1 : 0;
  unsigned long long b = __ballot(nz);
  if ((threadIdx.x & 63) == 0) atomicAdd(&scal[0], (int)__popcll(b));
}

// scal: [0]=nnz [1]=prune [2]=k [3]=prefix/Kstar [4]=rank/need [5]=eqcnt
__global__ void k_initsel(int* scal){
  int nnz = scal[0];
  double prod = (double)nnz * 0.3;        // IEEE-identical to Python
  scal[1] = ((int)prod != 0) ? 1 : 0;
  int k = (int)(prod + 1.0);
  scal[2] = k; scal[3] = 0; scal[4] = k;
}

__global__ void k_hist(const unsigned int* __restrict__ key, unsigned int* __restrict__ hist,
                       const int* __restrict__ scal, int pass){
  __shared__ unsigned int lh[256];
  int t = threadIdx.x;
  lh[t] = 0; __syncthreads();
  int i = blockIdx.x*256 + t;
  unsigned int kv = key[i];
  unsigned int pref = (unsigned int)scal[3];
  bool ok = (pass == 0) || ((kv >> (32 - 8*pass)) == pref);
  if (ok) atomicAdd(&lh[(kv >> (24 - 8*pass)) & 255u], 1u);
  __syncthreads();
  if (lh[t]) atomicAdd(&hist[t], lh[t]);
}

__global__ void k_select(unsigned int* __restrict__ hist, int* __restrict__ scal){
  __shared__ unsigned int h[256];
  int t = threadIdx.x;
  h[t] = hist[t];
  __syncthreads();
  if (t == 0){
    unsigned int r = (unsigned int)scal[4];
    unsigned int cum = 0, pref = (unsigned int)scal[3];
    for (int b = 0; b < 256; b++){
      unsigned int c = h[b];
      if (cum + c >= r){
        scal[3] = (int)((pref << 8) | (unsigned int)b);
        scal[4] = (int)(r - cum);
        break;
      }
      cum += c;
    }
  }
  __syncthreads();
  hist[t] = 0;  // ready for next pass
}

__global__ void k_mark(const unsigned int* __restrict__ key, int* __restrict__ scal,
                       int* __restrict__ rem, int* __restrict__ eqlist){
  if (!scal[1]) return;
  int i = blockIdx.x*256 + threadIdx.x;
  unsigned int Ks = (unsigned int)scal[3];
  unsigned int kv = key[i];
  if (kv < Ks) rem[i] = 1;
  else if (kv == Ks){
    int p = atomicAdd(&scal[5], 1);
    if (p < 4096) eqlist[p] = i;
  }
}

__global__ void k_ties(int* __restrict__ scal, int* __restrict__ eqlist, int* __restrict__ rem){
  if (!scal[1]) return;
  int m = scal[5]; if (m > 4096) m = 4096;
  int need = scal[4]; if (need > m) need = m;
  for (int it = 0; it < need; it++){          // lowest indices first (top_k tie rule)
    int best = 0x7FFFFFFF, bj = -1;
    for (int j = 0; j < m; j++){ int v = eqlist[j]; if (v < best){ best = v; bj = j; } }
    if (bj < 0) break;
    rem[best] = 1; eqlist[bj] = 0x7FFFFFFF;
  }
}

// Fused 5x parent-climb + edge finalize. The 5 Jacobi iterations of
// remove_nodes_func equal: first non-removed ancestor within 31 steps of the
// ORIGINAL parent chain, else the 31st ancestor (pointer-doubling: d5 = 2^5-1).
// rem[0]==0 guaranteed (node 0 never pruned), so p==0 terminates the walk.
__global__ void k_climb(const int* __restrict__ par_in, const int* __restrict__ rem,
                        int* __restrict__ srcF, int* __restrict__ dstF,
                        int* __restrict__ cnt){
  int e = blockIdx.x*256 + threadIdx.x;
  if (e >= E_EDGES) return;
  int s = e + 1;                       // edge_index row0 == arange(1, N)
  if (rem[s]){ srcF[e] = 0; dstF[e] = -1; return; }
  int p = par_in[e];
  for (int st = 0; st < 31 && rem[p]; st++) p = par_in[p-1];
  srcF[e] = s;
  dstF[e] = p;
  atomicAdd(&cnt[p], 1);
}

__global__ void k_scan1(const int* __restrict__ cnt, int* __restrict__ offs,
                        int* __restrict__ bsum){
  int b = blockIdx.x, t = threadIdx.x, i = b*256 + t;
  int v = cnt[i];
  int lane = t & 63, wv = t >> 6;
  int xv = v;
  for (int o2 = 1; o2 < 64; o2 <<= 1){ int y = __shfl_up(xv, o2); if (lane >= o2) xv += y; }
  __shared__ int wt_[4];
  if (lane == 63) wt_[wv] = xv;
  __syncthreads();
  int add = 0;
  for (int k2 = 0; k2 < wv; k2++) add += wt_[k2];
  offs[i] = xv + add - v;
  if (t == 255) bsum[b] = xv + add;
}

__global__ void k_scan2(int* __restrict__ bsum){
  int t = threadIdx.x;
  int v = bsum[t];
  int lane = t & 63, wv = t >> 6;
  int xv = v;
  for (int o2 = 1; o2 < 64; o2 <<= 1){ int y = __shfl_up(xv, o2); if (lane >= o2) xv += y; }
  __shared__ int wt_[4];
  if (lane == 63) wt_[wv] = xv;
  __syncthreads();
  int add = 0;
  for (int k2 = 0; k2 < wv; k2++) add += wt_[k2];
  bsum[t] = xv + add - v;  // exclusive
}

__global__ void k_scan3(int* __restrict__ offs, const int* __restrict__ bsum,
                        int* __restrict__ cur){
  int b = blockIdx.x, t = threadIdx.x, i = b*256 + t;
  int v = offs[i] + bsum[b];
  offs[i] = v; cur[i] = v;
}

__global__ void k_fill(const int* __restrict__ dstF, int* __restrict__ cur,
                       int* __restrict__ elist){
  int e = blockIdx.x*256 + threadIdx.x;
  if (e >= E_EDGES) return;
  int d = dstF[e]; if (d < 0) return;
  int pos = atomicAdd(&cur[d], 1);
  elist[pos] = e;
}

// gat_w[0:1024][:] -> bf16 transposed (wt[j][k] = gat_w[k][j])
__global__ void k_wt(const float* __restrict__ gw, unsigned short* __restrict__ wtb){
  __shared__ float tile[32][33];
  int kt = blockIdx.x*32, jt = blockIdx.y*32;
  int tx = threadIdx.x, ty = threadIdx.y;    // (32,8)
  for (int r = ty; r < 32; r += 8) tile[r][tx] = gw[(size_t)(kt+r)*JDIM + jt + tx];
  __syncthreads();
  for (int r = ty; r < 32; r += 8) wtb[(size_t)(jt+r)*KDIM + kt + tx] = f2bf(tile[tx][r]);
}

// tc[t][j] = sum_c gelu(emb_w[t][c]+emb_b[c]) * gat_w[1024+c][j]  (2 distinct type rows)
__global__ void k_tc(const float* __restrict__ embw, const float* __restrict__ embb,
                     const float* __restrict__ gw, float* __restrict__ tc){
  __shared__ float eg[2][DOUT];
  int t = threadIdx.x;
  eg[0][t] = gelu_f(embw[t] + embb[t]);
  eg[1][t] = gelu_f(embw[DOUT + t] + embb[t]);
  __syncthreads();
  int g = blockIdx.x*256 + t;   // 0..2047
  int te = g >> 10, j = g & 1023;
  float acc = 0.f;
  #pragma unroll 8
  for (int c = 0; c < DOUT; c++){
    acc += eg[te][c] * gw[(size_t)(KDIM + c)*JDIM + j];
  }
  tc[te*JDIM + j] = acc;
}

// 256x256-tile, BK=64, 8-wave, double-buffered bf16 MFMA GEMM with T4
// counted-vmcnt pipeline: the ready-wait is vmcnt(8) (only tile t's 8 loads,
// issued a full iteration earlier) instead of __syncthreads' vmcnt(0) drain
// (which stalled on tile t+1's just-issued loads every iteration).
#define BKG 64
#define CFENCE() asm volatile("" ::: "memory")
__global__ __launch_bounds__(512, 2) void k_gemm(const unsigned short* __restrict__ xs,
    const unsigned short* __restrict__ wtb, const float* __restrict__ tc,
    const int* __restrict__ tid, unsigned short* __restrict__ hmat){
  __shared__ unsigned short As[2][256*BKG];   // 32 KB per buffer
  __shared__ unsigned short Bs[2][256*BKG];   // total 128 KB LDS
  int bid = blockIdx.x;
  // bijective XCD swizzle (1024 blocks, 1024%8==0): the 4 jb-blocks sharing an
  // A-panel land on consecutive slots of one XCD -> A fetched from HBM once.
  int xcd = bid & 7, tq = bid >> 3;
  int jb = tq & 3, ip = (tq >> 2)*8 + xcd;     // ip in 0..255, jb in 0..3
  int rowbase = ip*256, colbase = jb*256;
  int t = threadIdx.x, wave = t >> 6, lane = t & 63;
  int wm = (wave >> 2)*128, wn = (wave & 3)*64;   // 2x4 wave grid, 128x64 per wave
  floatx4 acc[8][4];
  floatx4 zero = {0.f, 0.f, 0.f, 0.f};
  #pragma unroll
  for (int a = 0; a < 8; a++)
    #pragma unroll
    for (int b = 0; b < 4; b++) acc[a][b] = zero;

  // staging geometry: per round r (0..3), wave w stages chunk ci=r*8+w
  // = rows [ci*8, ci*8+8) x 64 cols; lane l covers LDS bytes ci*1024 + l*16.
  // 8 global_load_lds per wave per tile (4 rounds x {A,B}).
  int srow = lane >> 3;        // 0..7 row within chunk
  int scol = (lane & 7)*8;     // element col offset (8 bf16 = 16 B)

  auto STAGE = [&](int buf, int kt){
    int k0 = kt*BKG;
    #pragma unroll
    for (int r = 0; r < 4; r++){
      int ci = r*8 + wave;
      int row = ci*8 + srow;
      const unsigned short* ga = xs  + (size_t)(rowbase + row)*KDIM + k0 + scol;
      __builtin_amdgcn_global_load_lds((const __attribute__((address_space(1))) void*)ga,
          (__attribute__((address_space(3))) void*)(&As[buf][ci*512 + lane*8]), 16, 0, 0);
      const unsigned short* gb = wtb + (size_t)(colbase + row)*KDIM + k0 + scol;
      __builtin_amdgcn_global_load_lds((const __attribute__((address_space(1))) void*)gb,
          (__attribute__((address_space(3))) void*)(&Bs[buf][ci*512 + lane*8]), 16, 0, 0);
    }
  };

  int rr = lane & 15, rq = (lane >> 4)*8;
  auto COMPUTE = [&](int buf){
    #pragma unroll
    for (int ks = 0; ks < 2; ks++){
      short8 af[8], bfr[4];
      #pragma unroll
      for (int mi = 0; mi < 8; mi++)
        af[mi]  = *(const short8*)(&As[buf][(wm + mi*16 + rr)*BKG + ks*32 + rq]);
      #pragma unroll
      for (int ni = 0; ni < 4; ni++)
        bfr[ni] = *(const short8*)(&Bs[buf][(wn + ni*16 + rr)*BKG + ks*32 + rq]);
      #pragma unroll
      for (int mi = 0; mi < 8; mi++)
        #pragma unroll
        for (int ni = 0; ni < 4; ni++)
          acc[mi][ni] = __builtin_amdgcn_mfma_f32_16x16x32_bf16(af[mi], bfr[ni], acc[mi][ni], 0, 0, 0);
    }
  };

  const int NT = KDIM / BKG;   // 16 K-tiles
  STAGE(0, 0);                 // 8 loads in flight (tile 0)
  int cur = 0;
  for (int kt = 0; kt < NT; kt++){
    if (kt < NT - 1){
      STAGE(cur ^ 1, kt + 1);  // +8 -> 16 outstanding (tiles kt, kt+1)
      // wait ONLY tile kt's 8 (oldest); tile kt+1 stays in flight across MFMA
      asm volatile("s_waitcnt vmcnt(8)" ::: "memory");
    } else {
      asm volatile("s_waitcnt vmcnt(0)" ::: "memory");   // last tile: drain
    }
    __builtin_amdgcn_s_barrier();   // all waves' tile-kt loads landed
    CFENCE();
    COMPUTE(cur);
    if (kt < NT - 1){
      CFENCE();
      __builtin_amdgcn_s_barrier(); // readers done -> next iter may stage buf cur
      CFENCE();
    }
    cur ^= 1;
  }

  int q = lane >> 4, cc = lane & 15;
  #pragma unroll
  for (int mi = 0; mi < 8; mi++){
    #pragma unroll
    for (int reg = 0; reg < 4; reg++){
      int rowg = rowbase + wm + mi*16 + q*4 + reg;
      int tt = tid[rowg];
      #pragma unroll
      for (int ni = 0; ni < 4; ni++){
        int col = colbase + wn + ni*16 + cc;
        float v = acc[mi][ni][reg] + tc[tt*JDIM + col];
        hmat[(size_t)rowg*JDIM + col] = f2bf(v);
      }
    }
  }
}

// per-node softmax (in-block max+sum) + aggregate + gelu
__global__ void k_agg(const unsigned short* __restrict__ hmat, const int* __restrict__ srcF,
                      const float* __restrict__ asrc, const float* __restrict__ adst,
                      const int* __restrict__ offs, const int* __restrict__ cnt,
                      const int* __restrict__ elist, const float* __restrict__ gatb,
                      const int* __restrict__ scal, float* __restrict__ out){
  int n = blockIdx.x, t = threadIdx.x;
  int o0 = offs[n], c_ = cnt[n];
  __shared__ float mh_s[4], sh_s[4];
  int wave = t >> 6, lane = t & 63;
  if (wave == 0){
    int hd = lane >> 4, r = lane & 15;       // 16 lanes per head
    float adn = adst[n*HEADS + hd];
    float aself = leaky(asrc[n*HEADS + hd] + adn);
    float mx = aself;
    for (int q2 = r; q2 < c_; q2 += 16){
      int e = elist[o0 + q2];
      int s = srcF[e];
      float al = leaky(asrc[s*HEADS + hd] + adn);
      mx = fmaxf(mx, al);
    }
    for (int m2 = 1; m2 < 16; m2 <<= 1) mx = fmaxf(mx, __shfl_xor(mx, m2));
    float sm = 0.f;
    for (int q2 = r; q2 < c_; q2 += 16){
      int e = elist[o0 + q2];
      int s = srcF[e];
      float al = leaky(asrc[s*HEADS + hd] + adn);
      sm += expf(al - mx);
    }
    for (int m2 = 1; m2 < 16; m2 <<= 1) sm += __shfl_xor(sm, m2);
    if (r == 0){
      float wself = 1.f;
      if (n == 0 && scal[1]) wself = 1.f + (float)scal[2];  // k masked (0,0) copies + self
      sm += wself * expf(aself - mx);
      mh_s[hd] = mx; sh_s[hd] = sm + 1e-16f;
    }
  }
  __syncthreads();
  int hd = t >> 6;                     // 4*t in [hd*256,(hd+1)*256)
  float mh = mh_s[hd];
  float sh = sh_s[hd];
  float adn = adst[n*HEADS + hd];
  float a0 = 0.f, a1 = 0.f, a2 = 0.f, a3 = 0.f;
  { // self-loop (+ k masked copies on node 0)
    float al = leaky(asrc[n*HEADS + hd] + adn);
    float coef = expf(al - mh) / sh;
    if (n == 0 && scal[1]) coef *= (1.f + (float)scal[2]);
    ushort4 hv = *(const ushort4*)(hmat + (size_t)n*JDIM + 4*t);
    a0 += coef*bf2f(hv.x); a1 += coef*bf2f(hv.y); a2 += coef*bf2f(hv.z); a3 += coef*bf2f(hv.w);
  }
  for (int q2 = 0; q2 < c_; q2++){
    int e = elist[o0 + q2];
    int s = srcF[e];
    float al = leaky(asrc[s*HEADS + hd] + adn);
    float coef = expf(al - mh) / sh;
    ushort4 hv = *(const ushort4*)(hmat + (size_t)s*JDIM + 4*t);
    a0 += coef*bf2f(hv.x); a1 += coef*bf2f(hv.y); a2 += coef*bf2f(hv.z); a3 += coef*bf2f(hv.w);
  }
  const float4 gb = *(const float4*)(gatb + 4*t);
  float4 ov;
  ov.x = gelu_f(a0 + gb.x); ov.y = gelu_f(a1 + gb.y);
  ov.z = gelu_f(a2 + gb.z); ov.w = gelu_f(a3 + gb.w);
  *(float4*)(out + (size_t)n*JDIM + 4*t) = ov;
}

__global__ void k_nm(const float* __restrict__ nmask, const int* __restrict__ rem,
                     float* __restrict__ nmout){
  int i = blockIdx.x*256 + threadIdx.x;
  float u = (i == 0) ? 1.f : (1.f - (float)rem[i]);
  nmout[i] = nmask[i] * u;
}

extern "C" void kernel_launch(void* const* d_in, const int* in_sizes, int n_in,
                              void* d_out, int out_size, void* d_ws, size_t ws_size,
                              hipStream_t stream){
  (void)in_sizes; (void)n_in; (void)out_size; (void)ws_size;
  const float* x    = (const float*)d_in[0];
  const int*  eidx  = (const int*)d_in[1];
  const float* sr   = (const float*)d_in[3];
  const float* nmask= (const float*)d_in[4];
  const int*  tid   = (const int*)d_in[5];
  const float* sw   = (const float*)d_in[6];
  const float* sb   = (const float*)d_in[7];
  const float* embw = (const float*)d_in[8];
  const float* embb = (const float*)d_in[9];
  const float* gw   = (const float*)d_in[10];
  const float* atts = (const float*)d_in[11];
  const float* attd = (const float*)d_in[12];
  const float* gatb = (const float*)d_in[13];
  float* out = (float*)d_out;

  char* w = (char*)d_ws;
  size_t o = 0;
  auto alloc = [&](size_t bytes){ size_t r = o; o += (bytes + 255) & ~(size_t)255; return r; };
  // zeroed region (single memset)
  size_t o_cnt  = alloc((size_t)N_NODES*4);
  size_t o_rem  = alloc((size_t)N_NODES*4);
  size_t o_hist = alloc(256*4);
  size_t o_scal = alloc(64);
  size_t o_eq   = alloc(4096*4);
  size_t zero_bytes = o;
  // not zeroed
  size_t o_score= alloc((size_t)N_NODES*4);
  size_t o_key  = alloc((size_t)N_NODES*4);
  size_t o_srcF = alloc((size_t)E_EDGES*4);
  size_t o_dstF = alloc((size_t)E_EDGES*4);
  size_t o_off  = alloc((size_t)N_NODES*4);
  size_t o_cur  = alloc((size_t)N_NODES*4);
  size_t o_el   = alloc((size_t)E_EDGES*4);
  size_t o_bsum = alloc(256*4);
  size_t o_asrc = alloc((size_t)N_NODES*HEADS*4);
  size_t o_adst = alloc((size_t)N_NODES*HEADS*4);
  size_t o_tc   = alloc((size_t)2*JDIM*4);
  size_t o_wats = alloc((size_t)KDIM*4*4);
  size_t o_watd = alloc((size_t)KDIM*4*4);
  size_t o_tatt = alloc(16*4);
  size_t o_wt   = alloc((size_t)JDIM*KDIM*2);
  size_t o_xs   = alloc((size_t)N_NODES*KDIM*2);
  size_t o_h    = alloc((size_t)N_NODES*JDIM*2);

  int* cnt   = (int*)(w + o_cnt);
  int* rem   = (int*)(w + o_rem);
  unsigned int* hist = (unsigned int*)(w + o_hist);
  int* scal  = (int*)(w + o_scal);
  int* eqlist= (int*)(w + o_eq);
  float* score = (float*)(w + o_score);
  unsigned int* key = (unsigned int*)(w + o_key);
  int* srcF = (int*)(w + o_srcF);
  int* dstF = (int*)(w + o_dstF);
  int* offs = (int*)(w + o_off);
  int* cur  = (int*)(w + o_cur);
  int* elist= (int*)(w + o_el);
  int* bsum = (int*)(w + o_bsum);
  float* asrc = (float*)(w + o_asrc);
  float* adst = (float*)(w + o_adst);
  float* tc = (float*)(w + o_tc);
  float* watt_s = (float*)(w + o_wats);
  float* watt_d = (float*)(w + o_watd);
  float* tatt = (float*)(w + o_tatt);
  unsigned short* wtb = (unsigned short*)(w + o_wt);
  unsigned short* xs  = (unsigned short*)(w + o_xs);
  unsigned short* hmat= (unsigned short*)(w + o_h);

  hipMemsetAsync(w, 0, zero_bytes, stream);

  // small precomputes first (only depend on weights)
  k_watt<<<256, 256, 0, stream>>>(gw, atts, attd, watt_s, watt_d);
  k_tc<<<8, 256, 0, stream>>>(embw, embb, gw, tc);
  k_tatt<<<1, 64, 0, stream>>>(tc, atts, attd, tatt);
  k_wt<<<dim3(32,32), dim3(32,8), 0, stream>>>(gw, wtb);

  k_prep<<<N_NODES/4, 256, 0, stream>>>(x, sr, nmask, sw, sb, watt_s, watt_d, tatt,
                                        tid, xs, score, key, asrc, adst);
  k_nnz<<<N_NODES/256, 256, 0, stream>>>(score, scal);
  k_initsel<<<1, 1, 0, stream>>>(scal);
  for (int p = 0; p < 4; p++){
    k_hist<<<N_NODES/256, 256, 0, stream>>>(key, hist, scal, p);
    k_select<<<1, 256, 0, stream>>>(hist, scal);
  }
  k_mark<<<N_NODES/256, 256, 0, stream>>>(key, scal, rem, eqlist);
  k_ties<<<1, 1, 0, stream>>>(scal, eqlist, rem);

  const int* par_in = eidx + E_EDGES;   // edge_index row 1
  int egrid = (E_EDGES + 255)/256;
  k_climb<<<egrid, 256, 0, stream>>>(par_in, rem, srcF, dstF, cnt);

  k_scan1<<<256, 256, 0, stream>>>(cnt, offs, bsum);
  k_scan2<<<1, 256, 0, stream>>>(bsum);
  k_scan3<<<256, 256, 0, stream>>>(offs, bsum, cur);
  k_fill<<<egrid, 256, 0, stream>>>(dstF, cur, elist);

  k_gemm<<<1024, 512, 0, stream>>>(xs, wtb, tc, tid, hmat);

  k_agg<<<N_NODES, 256, 0, stream>>>(hmat, srcF, asrc, adst, offs, cnt,
                                     elist, gatb, scal, out);
  k_nm<<<N_NODES/256, 256, 0, stream>>>(nmask, rem, out + (size_t)N_NODES*JDIM);
}

// Round 7
// 994.671 us; speedup vs baseline: 1.1786x; 1.0271x over previous
//
#include <hip/hip_runtime.h>
#include <cstdint>
#include <cstddef>

#define N_NODES 65536
#define E_EDGES 65535
#define DIN     512
#define KDIM    1024
#define JDIM    1024
#define HEADS   4
#define DOUT    256

typedef short   short8  __attribute__((ext_vector_type(8)));
typedef unsigned short ushort8 __attribute__((ext_vector_type(8)));
typedef float   floatx4 __attribute__((ext_vector_type(4)));

__device__ inline float bf2f(unsigned short u){
  union { unsigned int i; float f; } c; c.i = ((unsigned int)u) << 16; return c.f;
}
__device__ inline unsigned short f2bf(float f){
  union { float f; unsigned int i; } c; c.f = f;
  unsigned int r = c.i + 0x7FFFu + ((c.i >> 16) & 1u);
  return (unsigned short)(r >> 16);
}
// map float -> uint with same ordering (ascending)
__device__ inline unsigned int okey(float f){
  union { float f; unsigned int u; } c; c.f = f;
  return (c.u & 0x80000000u) ? ~c.u : (c.u | 0x80000000u);
}
__device__ inline float unokey(unsigned int k){
  union { unsigned int u; float f; } c;
  c.u = (k & 0x80000000u) ? (k ^ 0x80000000u) : ~k;
  return c.f;
}
__device__ inline float leaky(float x){ return x >= 0.f ? x : 0.2f * x; }
__device__ inline float gelu_f(float x){
  return 0.5f * x * (1.f + tanhf(0.7978845608028654f * (x + 0.044715f * x * x * x)));
}

// watt_s[k][hd] = sum_c gw[k][hd*256+c]*atts[hd][c];  watt_d same with attd
__global__ void k_watt(const float* __restrict__ gw, const float* __restrict__ atts,
                       const float* __restrict__ attd, float* __restrict__ watt_s,
                       float* __restrict__ watt_d){
  int wave = threadIdx.x >> 6, lane = threadIdx.x & 63;
  int k = blockIdx.x*4 + wave;           // 256 blocks x 4 waves = 1024 rows
  int hd = lane >> 4;
  const float* gr = gw + (size_t)k*JDIM + lane*16;
  float vs = 0.f, vd = 0.f;
  #pragma unroll
  for (int j = 0; j < 16; j += 4){
    float4 g = *(const float4*)(gr + j);
    float4 s = *(const float4*)(atts + lane*16 + j);   // flat idx == hd*DOUT+c
    float4 d = *(const float4*)(attd + lane*16 + j);
    vs += g.x*s.x + g.y*s.y + g.z*s.z + g.w*s.w;
    vd += g.x*d.x + g.y*d.y + g.z*d.z + g.w*d.w;
  }
  for (int m2 = 1; m2 < 16; m2 <<= 1){ vs += __shfl_xor(vs, m2); vd += __shfl_xor(vd, m2); }
  if ((lane & 15) == 0){ watt_s[k*4 + hd] = vs; watt_d[k*4 + hd] = vd; }
}

// tatt[ty*8 + sd*4 + hd] = sum_c tc[ty][hd*256+c] * att{sd}[hd][c]
__global__ void k_tatt(const float* __restrict__ tc, const float* __restrict__ atts,
                       const float* __restrict__ attd, float* __restrict__ tatt){
  int lane = threadIdx.x;   // 64
  for (int o = 0; o < 16; o++){
    int ty = o >> 3, sd = (o >> 2) & 1, hd = o & 3;
    const float* av = sd ? attd : atts;
    float p = 0.f;
    #pragma unroll
    for (int cc = 0; cc < 4; cc++){
      int c = lane*4 + cc;
      p += tc[ty*JDIM + hd*256 + c] * av[hd*DOUT + c];
    }
    for (int sdel = 32; sdel; sdel >>= 1) p += __shfl_down(p, sdel);
    if (lane == 0) tatt[o] = p;
  }
}

// ---------------- score + bf16 cast + key + att dots (wave-per-row) ----------------
// k-ownership is STRIDED: lane l owns k in {l, l+64, ..., l+960}. All global
// accesses (x, sr, sw scalar; watt_s/watt_d float4) are lane-coalesced.
__global__ void k_prep(const float* __restrict__ x, const float* __restrict__ sr,
                       const float* __restrict__ nmask, const float* __restrict__ sw,
                       const float* __restrict__ sb, const float* __restrict__ watt_s,
                       const float* __restrict__ watt_d, const float* __restrict__ tatt,
                       const int* __restrict__ tid, unsigned short* __restrict__ xs,
                       float* __restrict__ score, unsigned int* __restrict__ key,
                       float* __restrict__ asrc, float* __restrict__ adst){
  int lane = threadIdx.x & 63, wv = threadIdx.x >> 6;
  int i = blockIdx.x*4 + wv;
  const float* xr  = x  + (size_t)i*DIN;
  const float* srr = sr + (size_t)i*DIN;
  unsigned short* xo = xs + (size_t)i*KDIM;
  double part = 0.0;
  float4 ps = {0.f,0.f,0.f,0.f}, pd = {0.f,0.f,0.f,0.f};
  #pragma unroll
  for (int j = 0; j < 8; j++){
    int k = lane + 64*j;
    float va = xr[k];
    float vb = srr[k];
    part += (double)va*(double)sw[k] + (double)vb*(double)sw[512 + k];
    float4 sA = *(const float4*)(watt_s + (size_t)k*4);
    float4 dA = *(const float4*)(watt_d + (size_t)k*4);
    float4 sB = *(const float4*)(watt_s + (size_t)(512 + k)*4);
    float4 dB = *(const float4*)(watt_d + (size_t)(512 + k)*4);
    ps.x += va*sA.x + vb*sB.x; ps.y += va*sA.y + vb*sB.y;
    ps.z += va*sA.z + vb*sB.z; ps.w += va*sA.w + vb*sB.w;
    pd.x += va*dA.x + vb*dB.x; pd.y += va*dA.y + vb*dB.y;
    pd.z += va*dA.z + vb*dB.z; pd.w += va*dA.w + vb*dB.w;
    xo[k]       = f2bf(va);
    xo[512 + k] = f2bf(vb);
  }
  for (int sdel = 32; sdel; sdel >>= 1){
    part += __shfl_down(part, sdel);
    ps.x += __shfl_down(ps.x, sdel); ps.y += __shfl_down(ps.y, sdel);
    ps.z += __shfl_down(ps.z, sdel); ps.w += __shfl_down(ps.w, sdel);
    pd.x += __shfl_down(pd.x, sdel); pd.y += __shfl_down(pd.y, sdel);
    pd.z += __shfl_down(pd.z, sdel); pd.w += __shfl_down(pd.w, sdel);
  }
  if (lane == 0){
    float fs = (float)(part + (double)sb[0]);
    float s  = fs * nmask[i];
    score[i] = s;
    float v = (s == 0.f) ? __builtin_inff() : s;
    key[i] = okey(v);
    int tt = tid[i];
    float4 os = { ps.x + tatt[tt*8 + 0], ps.y + tatt[tt*8 + 1],
                  ps.z + tatt[tt*8 + 2], ps.w + tatt[tt*8 + 3] };
    float4 od = { pd.x + tatt[tt*8 + 4], pd.y + tatt[tt*8 + 5],
                  pd.z + tatt[tt*8 + 6], pd.w + tatt[tt*8 + 7] };
    *(float4*)(asrc + (size_t)i*HEADS) = os;
    *(float4*)(adst + (size_t)i*HEADS) = od;
  }
}

__global__ void k_nnz(const float* __restrict__ score, int* scal){
  int i = blockIdx.x*256 + threadIdx.x;
  int nz = (score[i] != 0.f) ? 1 : 0;
  unsigned long long b = __ballot(nz);
  if ((threadIdx.x & 63) == 0) atomicAdd(&scal[0], (int)__popcll(b));
}

// scal: [0]=nnz [1]=prune [2]=k [3]=prefix/Kstar [4]=rank/need [5]=eqcnt
__global__ void k_initsel(int* scal){
  int nnz = scal[0];
  double prod = (double)nnz * 0.3;        // IEEE-identical to Python
  scal[1] = ((int)prod != 0) ? 1 : 0;
  int k = (int)(prod + 1.0);
  scal[2] = k; scal[3] = 0; scal[4] = k;
}

__global__ void k_hist(const unsigned int* __restrict__ key, unsigned int* __restrict__ hist,
                       const int* __restrict__ scal, int pass){
  __shared__ unsigned int lh[256];
  int t = threadIdx.x;
  lh[t] = 0; __syncthreads();
  int i = blockIdx.x*256 + t;
  unsigned int kv = key[i];
  unsigned int pref = (unsigned int)scal[3];
  bool ok = (pass == 0) || ((kv >> (32 - 8*pass)) == pref);
  if (ok) atomicAdd(&lh[(kv >> (24 - 8*pass)) & 255u], 1u);
  __syncthreads();
  if (lh[t]) atomicAdd(&hist[t], lh[t]);
}

__global__ void k_select(unsigned int* __restrict__ hist, int* __restrict__ scal){
  __shared__ unsigned int h[256];
  int t = threadIdx.x;
  h[t] = hist[t];
  __syncthreads();
  if (t == 0){
    unsigned int r = (unsigned int)scal[4];
    unsigned int cum = 0, pref = (unsigned int)scal[3];
    for (int b = 0; b < 256; b++){
      unsigned int c = h[b];
      if (cum + c >= r){
        scal[3] = (int)((pref << 8) | (unsigned int)b);
        scal[4] = (int)(r - cum);
        break;
      }
      cum += c;
    }
  }
  __syncthreads();
  hist[t] = 0;  // ready for next pass
}

__global__ void k_mark(const unsigned int* __restrict__ key, int* __restrict__ scal,
                       int* __restrict__ rem, int* __restrict__ eqlist){
  if (!scal[1]) return;
  int i = blockIdx.x*256 + threadIdx.x;
  unsigned int Ks = (unsigned int)scal[3];
  unsigned int kv = key[i];
  if (kv < Ks) rem[i] = 1;
  else if (kv == Ks){
    int p = atomicAdd(&scal[5], 1);
    if (p < 4096) eqlist[p] = i;
  }
}

__global__ void k_ties(int* __restrict__ scal, int* __restrict__ eqlist, int* __restrict__ rem){
  if (!scal[1]) return;
  int m = scal[5]; if (m > 4096) m = 4096;
  int need = scal[4]; if (need > m) need = m;
  for (int it = 0; it < need; it++){          // lowest indices first (top_k tie rule)
    int best = 0x7FFFFFFF, bj = -1;
    for (int j = 0; j < m; j++){ int v = eqlist[j]; if (v < best){ best = v; bj = j; } }
    if (bj < 0) break;
    rem[best] = 1; eqlist[bj] = 0x7FFFFFFF;
  }
}

// Fused 5x parent-climb + edge finalize. The 5 Jacobi iterations of
// remove_nodes_func equal: first non-removed ancestor within 31 steps of the
// ORIGINAL parent chain, else the 31st ancestor (pointer-doubling: d5 = 2^5-1).
// rem[0]==0 guaranteed (node 0 never pruned), so p==0 terminates the walk.
__global__ void k_climb(const int* __restrict__ par_in, const int* __restrict__ rem,
                        int* __restrict__ srcF, int* __restrict__ dstF,
                        int* __restrict__ cnt){
  int e = blockIdx.x*256 + threadIdx.x;
  if (e >= E_EDGES) return;
  int s = e + 1;                       // edge_index row0 == arange(1, N)
  if (rem[s]){ srcF[e] = 0; dstF[e] = -1; return; }
  int p = par_in[e];
  for (int st = 0; st < 31 && rem[p]; st++) p = par_in[p-1];
  srcF[e] = s;
  dstF[e] = p;
  atomicAdd(&cnt[p], 1);
}

__global__ void k_scan1(const int* __restrict__ cnt, int* __restrict__ offs,
                        int* __restrict__ bsum){
  int b = blockIdx.x, t = threadIdx.x, i = b*256 + t;
  int v = cnt[i];
  int lane = t & 63, wv = t >> 6;
  int xv = v;
  for (int o2 = 1; o2 < 64; o2 <<= 1){ int y = __shfl_up(xv, o2); if (lane >= o2) xv += y; }
  __shared__ int wt_[4];
  if (lane == 63) wt_[wv] = xv;
  __syncthreads();
  int add = 0;
  for (int k2 = 0; k2 < wv; k2++) add += wt_[k2];
  offs[i] = xv + add - v;
  if (t == 255) bsum[b] = xv + add;
}

__global__ void k_scan2(int* __restrict__ bsum){
  int t = threadIdx.x;
  int v = bsum[t];
  int lane = t & 63, wv = t >> 6;
  int xv = v;
  for (int o2 = 1; o2 < 64; o2 <<= 1){ int y = __shfl_up(xv, o2); if (lane >= o2) xv += y; }
  __shared__ int wt_[4];
  if (lane == 63) wt_[wv] = xv;
  __syncthreads();
  int add = 0;
  for (int k2 = 0; k2 < wv; k2++) add += wt_[k2];
  bsum[t] = xv + add - v;  // exclusive
}

__global__ void k_scan3(int* __restrict__ offs, const int* __restrict__ bsum,
                        int* __restrict__ cur){
  int b = blockIdx.x, t = threadIdx.x, i = b*256 + t;
  int v = offs[i] + bsum[b];
  offs[i] = v; cur[i] = v;
}

__global__ void k_fill(const int* __restrict__ dstF, int* __restrict__ cur,
                       int* __restrict__ elist){
  int e = blockIdx.x*256 + threadIdx.x;
  if (e >= E_EDGES) return;
  int d = dstF[e]; if (d < 0) return;
  int pos = atomicAdd(&cur[d], 1);
  elist[pos] = e;
}

// gat_w[0:1024][:] -> bf16 transposed (wt[j][k] = gat_w[k][j])
__global__ void k_wt(const float* __restrict__ gw, unsigned short* __restrict__ wtb){
  __shared__ float tile[32][33];
  int kt = blockIdx.x*32, jt = blockIdx.y*32;
  int tx = threadIdx.x, ty = threadIdx.y;    // (32,8)
  for (int r = ty; r < 32; r += 8) tile[r][tx] = gw[(size_t)(kt+r)*JDIM + jt + tx];
  __syncthreads();
  for (int r = ty; r < 32; r += 8) wtb[(size_t)(jt+r)*KDIM + kt + tx] = f2bf(tile[tx][r]);
}

// tc[t][j] = sum_c gelu(emb_w[t][c]+emb_b[c]) * gat_w[1024+c][j]  (2 distinct type rows)
__global__ void k_tc(const float* __restrict__ embw, const float* __restrict__ embb,
                     const float* __restrict__ gw, float* __restrict__ tc){
  __shared__ float eg[2][DOUT];
  int t = threadIdx.x;
  eg[0][t] = gelu_f(embw[t] + embb[t]);
  eg[1][t] = gelu_f(embw[DOUT + t] + embb[t]);
  __syncthreads();
  int g = blockIdx.x*256 + t;   // 0..2047
  int te = g >> 10, j = g & 1023;
  float acc = 0.f;
  #pragma unroll 8
  for (int c = 0; c < DOUT; c++){
    acc += eg[te][c] * gw[(size_t)(KDIM + c)*JDIM + j];
  }
  tc[te*JDIM + j] = acc;
}

// 256x256-tile, BK=64, 8-wave, double-buffered bf16 MFMA GEMM.
// T4: counted vmcnt(8) ready-wait (tile t+1's loads stay in flight).
// T2: XOR bank-swizzle (rule #21 form): LDS dest linear (global_load_lds
// requirement), global SOURCE column pre-swizzled, reads apply the same
// involution col ^ ((row&7)*8). Kills the 16-way ds_read_b128 conflict
// (rows are 128 B = 32 banks -> all rows alias the same bank set).
#define BKG 64
#define CFENCE() asm volatile("" ::: "memory")
__global__ __launch_bounds__(512, 2) void k_gemm(const unsigned short* __restrict__ xs,
    const unsigned short* __restrict__ wtb, const float* __restrict__ tc,
    const int* __restrict__ tid, unsigned short* __restrict__ hmat){
  __shared__ unsigned short As[2][256*BKG];   // 32 KB per buffer
  __shared__ unsigned short Bs[2][256*BKG];   // total 128 KB LDS
  int bid = blockIdx.x;
  // bijective XCD swizzle (1024 blocks, 1024%8==0): the 4 jb-blocks sharing an
  // A-panel land on consecutive slots of one XCD -> A fetched from HBM once.
  int xcd = bid & 7, tq = bid >> 3;
  int jb = tq & 3, ip = (tq >> 2)*8 + xcd;     // ip in 0..255, jb in 0..3
  int rowbase = ip*256, colbase = jb*256;
  int t = threadIdx.x, wave = t >> 6, lane = t & 63;
  int wm = (wave >> 2)*128, wn = (wave & 3)*64;   // 2x4 wave grid, 128x64 per wave
  floatx4 acc[8][4];
  floatx4 zero = {0.f, 0.f, 0.f, 0.f};
  #pragma unroll
  for (int a = 0; a < 8; a++)
    #pragma unroll
    for (int b = 0; b < 4; b++) acc[a][b] = zero;

  // staging geometry: per round r (0..3), wave w stages chunk ci=r*8+w
  // = rows [ci*8, ci*8+8) x 64 cols; lane l writes LDS bytes ci*1024 + l*16
  // (linear, as global_load_lds requires). The GLOBAL column is pre-swizzled:
  // global element (row, c) lands at LDS element row*64 + (c ^ ((row&7)*8)).
  int srow = lane >> 3;                  // 0..7 row within chunk
  int scol = ((lane & 7) ^ srow) * 8;    // pre-swizzled global col (elements)

  auto STAGE = [&](int buf, int kt){
    int k0 = kt*BKG;
    #pragma unroll
    for (int r = 0; r < 4; r++){
      int ci = r*8 + wave;
      int row = ci*8 + srow;
      const unsigned short* ga = xs  + (size_t)(rowbase + row)*KDIM + k0 + scol;
      __builtin_amdgcn_global_load_lds((const __attribute__((address_space(1))) void*)ga,
          (__attribute__((address_space(3))) void*)(&As[buf][ci*512 + lane*8]), 16, 0, 0);
      const unsigned short* gb = wtb + (size_t)(colbase + row)*KDIM + k0 + scol;
      __builtin_amdgcn_global_load_lds((const __attribute__((address_space(1))) void*)gb,
          (__attribute__((address_space(3))) void*)(&Bs[buf][ci*512 + lane*8]), 16, 0, 0);
    }
  };

  int rr = lane & 15, rq = (lane >> 4)*8;
  int swz = (rr & 7)*8;                  // read-side involution (same XOR)
  auto COMPUTE = [&](int buf){
    #pragma unroll
    for (int ks = 0; ks < 2; ks++){
      int col = (ks*32 + rq) ^ swz;
      short8 af[8], bfr[4];
      #pragma unroll
      for (int mi = 0; mi < 8; mi++)
        af[mi]  = *(const short8*)(&As[buf][(wm + mi*16 + rr)*BKG + col]);
      #pragma unroll
      for (int ni = 0; ni < 4; ni++)
        bfr[ni] = *(const short8*)(&Bs[buf][(wn + ni*16 + rr)*BKG + col]);
      #pragma unroll
      for (int mi = 0; mi < 8; mi++)
        #pragma unroll
        for (int ni = 0; ni < 4; ni++)
          acc[mi][ni] = __builtin_amdgcn_mfma_f32_16x16x32_bf16(af[mi], bfr[ni], acc[mi][ni], 0, 0, 0);
    }
  };

  const int NT = KDIM / BKG;   // 16 K-tiles
  STAGE(0, 0);                 // 8 loads in flight (tile 0)
  int cur = 0;
  for (int kt = 0; kt < NT; kt++){
    if (kt < NT - 1){
      STAGE(cur ^ 1, kt + 1);  // +8 -> 16 outstanding (tiles kt, kt+1)
      // wait ONLY tile kt's 8 (oldest); tile kt+1 stays in flight across MFMA
      asm volatile("s_waitcnt vmcnt(8)" ::: "memory");
    } else {
      asm volatile("s_waitcnt vmcnt(0)" ::: "memory");   // last tile: drain
    }
    __builtin_amdgcn_s_barrier();   // all waves' tile-kt loads landed
    CFENCE();
    COMPUTE(cur);
    if (kt < NT - 1){
      CFENCE();
      __builtin_amdgcn_s_barrier(); // readers done -> next iter may stage buf cur
      CFENCE();
    }
    cur ^= 1;
  }

  int q = lane >> 4, cc = lane & 15;
  #pragma unroll
  for (int mi = 0; mi < 8; mi++){
    #pragma unroll
    for (int reg = 0; reg < 4; reg++){
      int rowg = rowbase + wm + mi*16 + q*4 + reg;
      int tt = tid[rowg];
      #pragma unroll
      for (int ni = 0; ni < 4; ni++){
        int col = colbase + wn + ni*16 + cc;
        float v = acc[mi][ni][reg] + tc[tt*JDIM + col];
        hmat[(size_t)rowg*JDIM + col] = f2bf(v);
      }
    }
  }
}

// per-node softmax (in-block max+sum) + aggregate + gelu
__global__ void k_agg(const unsigned short* __restrict__ hmat, const int* __restrict__ srcF,
                      const float* __restrict__ asrc, const float* __restrict__ adst,
                      const int* __restrict__ offs, const int* __restrict__ cnt,
                      const int* __restrict__ elist, const float* __restrict__ gatb,
                      const int* __restrict__ scal, float* __restrict__ out){
  int n = blockIdx.x, t = threadIdx.x;
  int o0 = offs[n], c_ = cnt[n];
  __shared__ float mh_s[4], sh_s[4];
  int wave = t >> 6, lane = t & 63;
  if (wave == 0){
    int hd = lane >> 4, r = lane & 15;       // 16 lanes per head
    float adn = adst[n*HEADS + hd];
    float aself = leaky(asrc[n*HEADS + hd] + adn);
    float mx = aself;
    for (int q2 = r; q2 < c_; q2 += 16){
      int e = elist[o0 + q2];
      int s = srcF[e];
      float al = leaky(asrc[s*HEADS + hd] + adn);
      mx = fmaxf(mx, al);
    }
    for (int m2 = 1; m2 < 16; m2 <<= 1) mx = fmaxf(mx, __shfl_xor(mx, m2));
    float sm = 0.f;
    for (int q2 = r; q2 < c_; q2 += 16){
      int e = elist[o0 + q2];
      int s = srcF[e];
      float al = leaky(asrc[s*HEADS + hd] + adn);
      sm += expf(al - mx);
    }
    for (int m2 = 1; m2 < 16; m2 <<= 1) sm += __shfl_xor(sm, m2);
    if (r == 0){
      float wself = 1.f;
      if (n == 0 && scal[1]) wself = 1.f + (float)scal[2];  // k masked (0,0) copies + self
      sm += wself * expf(aself - mx);
      mh_s[hd] = mx; sh_s[hd] = sm + 1e-16f;
    }
  }
  __syncthreads();
  int hd = t >> 6;                     // 4*t in [hd*256,(hd+1)*256)
  float mh = mh_s[hd];
  float sh = sh_s[hd];
  float adn = adst[n*HEADS + hd];
  float a0 = 0.f, a1 = 0.f, a2 = 0.f, a3 = 0.f;
  { // self-loop (+ k masked copies on node 0)
    float al = leaky(asrc[n*HEADS + hd] + adn);
    float coef = expf(al - mh) / sh;
    if (n == 0 && scal[1]) coef *= (1.f + (float)scal[2]);
    ushort4 hv = *(const ushort4*)(hmat + (size_t)n*JDIM + 4*t);
    a0 += coef*bf2f(hv.x); a1 += coef*bf2f(hv.y); a2 += coef*bf2f(hv.z); a3 += coef*bf2f(hv.w);
  }
  for (int q2 = 0; q2 < c_; q2++){
    int e = elist[o0 + q2];
    int s = srcF[e];
    float al = leaky(asrc[s*HEADS + hd] + adn);
    float coef = expf(al - mh) / sh;
    ushort4 hv = *(const ushort4*)(hmat + (size_t)s*JDIM + 4*t);
    a0 += coef*bf2f(hv.x); a1 += coef*bf2f(hv.y); a2 += coef*bf2f(hv.z); a3 += coef*bf2f(hv.w);
  }
  const float4 gb = *(const float4*)(gatb + 4*t);
  float4 ov;
  ov.x = gelu_f(a0 + gb.x); ov.y = gelu_f(a1 + gb.y);
  ov.z = gelu_f(a2 + gb.z); ov.w = gelu_f(a3 + gb.w);
  *(float4*)(out + (size_t)n*JDIM + 4*t) = ov;
}

__global__ void k_nm(const float* __restrict__ nmask, const int* __restrict__ rem,
                     float* __restrict__ nmout){
  int i = blockIdx.x*256 + threadIdx.x;
  float u = (i == 0) ? 1.f : (1.f - (float)rem[i]);
  nmout[i] = nmask[i] * u;
}

extern "C" void kernel_launch(void* const* d_in, const int* in_sizes, int n_in,
                              void* d_out, int out_size, void* d_ws, size_t ws_size,
                              hipStream_t stream){
  (void)in_sizes; (void)n_in; (void)out_size; (void)ws_size;
  const float* x    = (const float*)d_in[0];
  const int*  eidx  = (const int*)d_in[1];
  const float* sr   = (const float*)d_in[3];
  const float* nmask= (const float*)d_in[4];
  const int*  tid   = (const int*)d_in[5];
  const float* sw   = (const float*)d_in[6];
  const float* sb   = (const float*)d_in[7];
  const float* embw = (const float*)d_in[8];
  const float* embb = (const float*)d_in[9];
  const float* gw   = (const float*)d_in[10];
  const float* atts = (const float*)d_in[11];
  const float* attd = (const float*)d_in[12];
  const float* gatb = (const float*)d_in[13];
  float* out = (float*)d_out;

  char* w = (char*)d_ws;
  size_t o = 0;
  auto alloc = [&](size_t bytes){ size_t r = o; o += (bytes + 255) & ~(size_t)255; return r; };
  // zeroed region (single memset)
  size_t o_cnt  = alloc((size_t)N_NODES*4);
  size_t o_rem  = alloc((size_t)N_NODES*4);
  size_t o_hist = alloc(256*4);
  size_t o_scal = alloc(64);
  size_t o_eq   = alloc(4096*4);
  size_t zero_bytes = o;
  // not zeroed
  size_t o_score= alloc((size_t)N_NODES*4);
  size_t o_key  = alloc((size_t)N_NODES*4);
  size_t o_srcF = alloc((size_t)E_EDGES*4);
  size_t o_dstF = alloc((size_t)E_EDGES*4);
  size_t o_off  = alloc((size_t)N_NODES*4);
  size_t o_cur  = alloc((size_t)N_NODES*4);
  size_t o_el   = alloc((size_t)E_EDGES*4);
  size_t o_bsum = alloc(256*4);
  size_t o_asrc = alloc((size_t)N_NODES*HEADS*4);
  size_t o_adst = alloc((size_t)N_NODES*HEADS*4);
  size_t o_tc   = alloc((size_t)2*JDIM*4);
  size_t o_wats = alloc((size_t)KDIM*4*4);
  size_t o_watd = alloc((size_t)KDIM*4*4);
  size_t o_tatt = alloc(16*4);
  size_t o_wt   = alloc((size_t)JDIM*KDIM*2);
  size_t o_xs   = alloc((size_t)N_NODES*KDIM*2);
  size_t o_h    = alloc((size_t)N_NODES*JDIM*2);

  int* cnt   = (int*)(w + o_cnt);
  int* rem   = (int*)(w + o_rem);
  unsigned int* hist = (unsigned int*)(w + o_hist);
  int* scal  = (int*)(w + o_scal);
  int* eqlist= (int*)(w + o_eq);
  float* score = (float*)(w + o_score);
  unsigned int* key = (unsigned int*)(w + o_key);
  int* srcF = (int*)(w + o_srcF);
  int* dstF = (int*)(w + o_dstF);
  int* offs = (int*)(w + o_off);
  int* cur  = (int*)(w + o_cur);
  int* elist= (int*)(w + o_el);
  int* bsum = (int*)(w + o_bsum);
  float* asrc = (float*)(w + o_asrc);
  float* adst = (float*)(w + o_adst);
  float* tc = (float*)(w + o_tc);
  float* watt_s = (float*)(w + o_wats);
  float* watt_d = (float*)(w + o_watd);
  float* tatt = (float*)(w + o_tatt);
  unsigned short* wtb = (unsigned short*)(w + o_wt);
  unsigned short* xs  = (unsigned short*)(w + o_xs);
  unsigned short* hmat= (unsigned short*)(w + o_h);

  hipMemsetAsync(w, 0, zero_bytes, stream);

  // small precomputes first (only depend on weights)
  k_watt<<<256, 256, 0, stream>>>(gw, atts, attd, watt_s, watt_d);
  k_tc<<<8, 256, 0, stream>>>(embw, embb, gw, tc);
  k_tatt<<<1, 64, 0, stream>>>(tc, atts, attd, tatt);
  k_wt<<<dim3(32,32), dim3(32,8), 0, stream>>>(gw, wtb);

  k_prep<<<N_NODES/4, 256, 0, stream>>>(x, sr, nmask, sw, sb, watt_s, watt_d, tatt,
                                        tid, xs, score, key, asrc, adst);
  k_nnz<<<N_NODES/256, 256, 0, stream>>>(score, scal);
  k_initsel<<<1, 1, 0, stream>>>(scal);
  for (int p = 0; p < 4; p++){
    k_hist<<<N_NODES/256, 256, 0, stream>>>(key, hist, scal, p);
    k_select<<<1, 256, 0, stream>>>(hist, scal);
  }
  k_mark<<<N_NODES/256, 256, 0, stream>>>(key, scal, rem, eqlist);
  k_ties<<<1, 1, 0, stream>>>(scal, eqlist, rem);

  const int* par_in = eidx + E_EDGES;   // edge_index row 1
  int egrid = (E_EDGES + 255)/256;
  k_climb<<<egrid, 256, 0, stream>>>(par_in, rem, srcF, dstF, cnt);

  k_scan1<<<256, 256, 0, stream>>>(cnt, offs, bsum);
  k_scan2<<<1, 256, 0, stream>>>(bsum);
  k_scan3<<<256, 256, 0, stream>>>(offs, bsum, cur);
  k_fill<<<egrid, 256, 0, stream>>>(dstF, cur, elist);

  k_gemm<<<1024, 512, 0, stream>>>(xs, wtb, tc, tid, hmat);

  k_agg<<<N_NODES, 256, 0, stream>>>(hmat, srcF, asrc, adst, offs, cnt,
                                     elist, gatb, scal, out);
  k_nm<<<N_NODES/256, 256, 0, stream>>>(nmask, rem, out + (size_t)N_NODES*JDIM);
}